// Round 9
// baseline (1459.054 us; speedup 1.0000x reference)
//
#include <hip/hip_runtime.h>
#include <hip/hip_bf16.h>
#include <math.h>

#define DEV __device__ __forceinline__

static constexpr int LL = 4096;   // H*W
static constexpr int DD = 128;    // hidden
static constexpr int SEG = 128;   // segments per scan (32 positions each)
static constexpr float LOG2E = 1.4426950408889634f;
static constexpr float LN2 = 0.6931471805599453f;

DEV float silu_(float x) { return x / (1.f + __expf(-x)); }
// A&S 7.1.26 erf approximation, |err| <= 1.5e-7
DEV float erf_(float x) {
  const float ax = fabsf(x);
  const float t = 1.f / fmaf(0.3275911f, ax, 1.f);
  float p = fmaf(1.061405429f, t, -1.453152027f);
  p = fmaf(p, t, 1.421413741f);
  p = fmaf(p, t, -0.284496736f);
  p = fmaf(p, t, 0.254829592f);
  p = p * t;
  const float r = 1.f - p * __expf(-ax * ax);
  return x < 0.f ? -r : r;
}
DEV float gelu_(float x) { return 0.5f * x * (1.f + erf_(x * 0.7071067811865475f)); }
DEV float sp_(float x) {
  const float t = __builtin_amdgcn_exp2f(-fabsf(x) * LOG2E);
  return fmaxf(x, 0.f) + LN2 * __builtin_amdgcn_logf(1.f + t);
}

template <int CTRL>
DEV float dpp_add_(float x) {
  int y = __builtin_amdgcn_update_dpp(0, __float_as_int(x), CTRL, 0xF, 0xF, true);
  return x + __int_as_float(y);
}

// 64-position tiles (used by x_proj): tile s of direction k
DEV void seg_base_step(int k, int s, int& base, int& step) {
  if (k == 0)      { base = s * 64;        step = 1;   }
  else if (k == 1) { base = s;             step = 64;  }
  else if (k == 2) { base = 4095 - s * 64; step = -1;  }
  else             { base = 4095 - s;      step = -64; }
}

// 32-position scan segments: segment s of direction k covers scan positions
// [s*32, s*32+32); phys = base + i*step for i=0..31 (step signed).
DEV void seg32_base_step(int k, int s, int& base, int& step) {
  if (k == 0)      { base = s * 32;                      step = 1;   }
  else if (k == 1) { base = ((s & 1) * 32) * 64 + (s >> 1); step = 64; }
  else if (k == 2) { base = 4095 - s * 32;               step = -1;  }
  else {
    const int s2 = 127 - s;
    base = ((s2 & 1) * 32 + 31) * 64 + (s2 >> 1);
    step = -64;
  }
}

// ---------------- K1: in_proj: xz[m][b][c][l] = x @ in_w^T (c-major out) ----
__global__ __launch_bounds__(256) void k_inproj(
    const float* __restrict__ sar, const float* __restrict__ opt,
    const float* __restrict__ in_w, float* __restrict__ xz) {
  const int lt = blockIdx.x, ct = blockIdx.y, mb = blockIdx.z;
  const int m = mb >> 2;
  const float* __restrict__ x = (m == 0 ? opt : sar) + (size_t)(mb & 3) * (LL * DD);
  const float* __restrict__ W = in_w + (size_t)m * 256 * DD;
  __shared__ float sA[64][68];
  __shared__ float sW[64][68];
  const int tid = threadIdx.x;
  const int tc = tid & 15, tl = tid >> 4;
  float acc[4][4] = {};
  for (int db = 0; db < 2; ++db) {
    __syncthreads();
    for (int idx = tid; idx < 64 * 16; idx += 256) {
      const int r = idx >> 4, d4 = (idx & 15) << 2;
      *(float4*)&sA[r][d4] = *(const float4*)&x[(size_t)(lt * 64 + r) * DD + db * 64 + d4];
      *(float4*)&sW[r][d4] = *(const float4*)&W[(size_t)(ct * 64 + r) * DD + db * 64 + d4];
    }
    __syncthreads();
#pragma unroll 4
    for (int d = 0; d < 64; d += 4) {
      float4 a[4], w[4];
#pragma unroll
      for (int q = 0; q < 4; ++q) a[q] = *(const float4*)&sA[tl * 4 + q][d];
#pragma unroll
      for (int j = 0; j < 4; ++j) w[j] = *(const float4*)&sW[tc + 16 * j][d];
#pragma unroll
      for (int j = 0; j < 4; ++j)
#pragma unroll
        for (int q = 0; q < 4; ++q)
          acc[j][q] += a[q].x * w[j].x + a[q].y * w[j].y + a[q].z * w[j].z + a[q].w * w[j].w;
    }
  }
  float* __restrict__ dst = xz + ((size_t)mb * 256 + ct * 64) * LL + lt * 64;
#pragma unroll
  for (int j = 0; j < 4; ++j) {
    float4 v = make_float4(acc[j][0], acc[j][1], acc[j][2], acc[j][3]);
    *(float4*)&dst[(size_t)(tc + 16 * j) * LL + tl * 4] = v;
  }
}

// ---------------- K2: depthwise 3x3 SAME conv + bias + SiLU ---------------
__global__ __launch_bounds__(256) void k_conv(
    const float* __restrict__ xz, const float* __restrict__ conv_w,
    const float* __restrict__ conv_b, float* __restrict__ xc) {
  const int ht = blockIdx.x, dg = blockIdx.y, mb = blockIdx.z;
  const int m = mb >> 2;
  __shared__ float sIn[8][18][66];
  __shared__ float sOut[1024][8];
  const float* __restrict__ src = xz + ((size_t)mb * 256 + dg * 8) * LL;
  const int tid = threadIdx.x;
  for (int idx = tid; idx < 8 * 18 * 66; idx += 256) {
    const int dd = idx / (18 * 66);
    const int rem = idx - dd * (18 * 66);
    const int hh = rem / 66, ww = rem - hh * 66;
    const int h = ht * 16 + hh - 1, w = ww - 1;
    float v = 0.f;
    if (h >= 0 && h < 64 && w >= 0 && w < 64) v = src[(size_t)dd * LL + h * 64 + w];
    sIn[dd][hh][ww] = v;
  }
  __syncthreads();
  const int dd = tid & 7, wv = tid >> 3;
  const int dch = dg * 8 + dd;
  float wk[9];
#pragma unroll
  for (int t = 0; t < 9; ++t) wk[t] = conv_w[((size_t)m * DD + dch) * 9 + t];
  const float bias = conv_b[m * DD + dch];
  for (int hh = 0; hh < 16; ++hh) {
#pragma unroll
    for (int wh = 0; wh < 2; ++wh) {
      const int w = wv + wh * 32;
      float s = bias;
#pragma unroll
      for (int kh = 0; kh < 3; ++kh)
#pragma unroll
        for (int kw = 0; kw < 3; ++kw)
          s = fmaf(sIn[dd][hh + kh][w + kw], wk[kh * 3 + kw], s);
      sOut[hh * 64 + w][dd] = silu_(s);
    }
  }
  __syncthreads();
  float* __restrict__ dst = xc + (size_t)mb * LL * DD + dg * 8;
#pragma unroll
  for (int r = 0; r < 4; ++r) {
    const int pos = tid + r * 256;
    const int l = ht * 1024 + pos;
    *(float4*)&dst[(size_t)l * DD + 0] = *(const float4*)&sOut[pos][0];
    *(float4*)&dst[(size_t)l * DD + 4] = *(const float4*)&sOut[pos][4];
  }
}

// ---------------- K3: x_proj -> xdbl[mbk][l][24]  (l-major, contiguous) ---
__global__ __launch_bounds__(256) void k_xproj(
    const float* __restrict__ xc, const float* __restrict__ xproj_w,
    float* __restrict__ xdbl) {
  const int lt = blockIdx.x, k = blockIdx.y, mb = blockIdx.z;
  const int m = mb >> 2, mbk = mb * 4 + k;
  __shared__ float sX[64][132];
  __shared__ float sW[24][132];
  const int tid = threadIdx.x;
  const float* __restrict__ src = xc + (size_t)mb * LL * DD;
  int base, step;
  seg_base_step(k, lt, base, step);
  for (int idx = tid; idx < 64 * 32; idx += 256) {
    const int l = idx >> 5, d4 = (idx & 31) << 2;
    *(float4*)&sX[l][d4] = *(const float4*)&src[(size_t)(base + l * step) * DD + d4];
  }
  const float* __restrict__ Wsrc = xproj_w + ((size_t)m * 4 + k) * 24 * DD;
  for (int idx = tid; idx < 24 * 32; idx += 256) {
    const int r = idx >> 5, d4 = (idx & 31) << 2;
    *(float4*)&sW[r][d4] = *(const float4*)&Wsrc[(size_t)r * DD + d4];
  }
  __syncthreads();
  const int l = tid >> 2, cg = tid & 3;
  float acc[6] = {};
#pragma unroll 8
  for (int d = 0; d < 128; d += 4) {
    const float4 xv = *(const float4*)&sX[l][d];
#pragma unroll
    for (int j = 0; j < 6; ++j) {
      const float4 wv = *(const float4*)&sW[cg * 6 + j][d];
      acc[j] += xv.x * wv.x + xv.y * wv.y + xv.z * wv.z + xv.w * wv.w;
    }
  }
  float* __restrict__ dst = xdbl + ((size_t)mbk * LL + lt * 64 + l) * 24 + cg * 6;
#pragma unroll
  for (int j = 0; j < 6; ++j) dst[j] = acc[j];
}

// ============ single-pass selective scan with decoupled look-back =========
// Block (s, k, mb): loop1 local scan (h0=0, dt stashed in LDS) -> publish
// aggregate -> look back for prefix seed -> publish inclusive -> loop2
// produces y. blockIdx.x = s (fastest dispatch dim) so predecessors of any
// resident block were dispatched earlier -> forward progress guaranteed.

DEV void load_aln2(const float* __restrict__ Alogs, int m, int k, int d,
                   float* __restrict__ aln2, bool& fastp) {
  const float4 a0 = *(const float4*)&Alogs[((size_t)m * 512 + k * DD + d) * 8];
  const float4 a1 = *(const float4*)&Alogs[((size_t)m * 512 + k * DD + d) * 8 + 4];
  aln2[0] = -__expf(a0.x) * LOG2E; aln2[1] = -__expf(a0.y) * LOG2E;
  aln2[2] = -__expf(a0.z) * LOG2E; aln2[3] = -__expf(a0.w) * LOG2E;
  aln2[4] = -__expf(a1.x) * LOG2E; aln2[5] = -__expf(a1.y) * LOG2E;
  aln2[6] = -__expf(a1.z) * LOG2E; aln2[7] = -__expf(a1.w) * LOG2E;
  fastp = true;
#pragma unroll
  for (int n = 1; n < 8; ++n)
    fastp = fastp && (fabsf(aln2[n] - (float)(n + 1) * aln2[0]) <=
                      1e-4f * fabsf(aln2[n]) + 1e-12f);
}

template <bool FAST>
DEV void qpow_(float dt, const float* __restrict__ aln2, float* __restrict__ q) {
  if constexpr (FAST) {
    q[0] = __builtin_amdgcn_exp2f(dt * aln2[0]);
    q[1] = q[0] * q[0]; q[2] = q[1] * q[0]; q[3] = q[1] * q[1];
    q[4] = q[3] * q[0]; q[5] = q[3] * q[1]; q[6] = q[3] * q[2]; q[7] = q[3] * q[3];
  } else {
#pragma unroll
    for (int n = 0; n < 8; ++n) q[n] = __builtin_amdgcn_exp2f(dt * aln2[n]);
  }
}

template <bool FAST>
DEV void loop1_(const float* __restrict__ slds, float* __restrict__ sdt,
                const float* __restrict__ xs0, ptrdiff_t sstep,
                const float* __restrict__ aln2, const float* __restrict__ wreg,
                float bw, float* __restrict__ h, float& dtsum, int d) {
  float xreg[8];
#pragma unroll
  for (int t = 0; t < 8; ++t) xreg[t] = xs0[(ptrdiff_t)t * sstep];
#pragma unroll 8
  for (int j = 0; j < 32; ++j) {
    const float x = xreg[j & 7];
    if (j + 8 < 32) xreg[j & 7] = xs0[(ptrdiff_t)(j + 8) * sstep];
    const float4 t0 = *(const float4*)&slds[j * 24 + 0];
    const float4 t1 = *(const float4*)&slds[j * 24 + 4];
    float s = bw;
    s = fmaf(t0.x, wreg[0], s); s = fmaf(t0.y, wreg[1], s);
    s = fmaf(t0.z, wreg[2], s); s = fmaf(t0.w, wreg[3], s);
    s = fmaf(t1.x, wreg[4], s); s = fmaf(t1.y, wreg[5], s);
    s = fmaf(t1.z, wreg[6], s); s = fmaf(t1.w, wreg[7], s);
    const float dt = sp_(s);
    sdt[j * 128 + d] = dt;
    dtsum += dt;
    const float u = dt * x;
    float q[8];
    qpow_<FAST>(dt, aln2, q);
    const float4 b0 = *(const float4*)&slds[j * 24 + 8];
    const float4 b1 = *(const float4*)&slds[j * 24 + 12];
    h[0] = fmaf(h[0], q[0], u * b0.x);
    h[1] = fmaf(h[1], q[1], u * b0.y);
    h[2] = fmaf(h[2], q[2], u * b0.z);
    h[3] = fmaf(h[3], q[3], u * b0.w);
    h[4] = fmaf(h[4], q[4], u * b1.x);
    h[5] = fmaf(h[5], q[5], u * b1.y);
    h[6] = fmaf(h[6], q[6], u * b1.z);
    h[7] = fmaf(h[7], q[7], u * b1.w);
  }
}

template <bool FAST>
DEV void loop2_(const float* __restrict__ slds, const float* __restrict__ sdt,
                const float* __restrict__ xs0, ptrdiff_t sstep,
                const float* __restrict__ aln2, float dsv,
                float* __restrict__ h, float* __restrict__ yk, int d) {
  float xreg[8];
#pragma unroll
  for (int t = 0; t < 8; ++t) xreg[t] = xs0[(ptrdiff_t)t * sstep];
#pragma unroll 8
  for (int j = 0; j < 32; ++j) {
    const float x = xreg[j & 7];
    if (j + 8 < 32) xreg[j & 7] = xs0[(ptrdiff_t)(j + 8) * sstep];
    const float dt = sdt[j * 128 + d];
    const float u = dt * x;
    float q[8];
    qpow_<FAST>(dt, aln2, q);
    const float4 b0 = *(const float4*)&slds[j * 24 + 8];
    const float4 b1 = *(const float4*)&slds[j * 24 + 12];
    const float4 c0 = *(const float4*)&slds[j * 24 + 16];
    const float4 c1 = *(const float4*)&slds[j * 24 + 20];
    float y = dsv * x;
    h[0] = fmaf(h[0], q[0], u * b0.x); y = fmaf(h[0], c0.x, y);
    h[1] = fmaf(h[1], q[1], u * b0.y); y = fmaf(h[1], c0.y, y);
    h[2] = fmaf(h[2], q[2], u * b0.z); y = fmaf(h[2], c0.z, y);
    h[3] = fmaf(h[3], q[3], u * b0.w); y = fmaf(h[3], c0.w, y);
    h[4] = fmaf(h[4], q[4], u * b1.x); y = fmaf(h[4], c1.x, y);
    h[5] = fmaf(h[5], q[5], u * b1.y); y = fmaf(h[5], c1.y, y);
    h[6] = fmaf(h[6], q[6], u * b1.z); y = fmaf(h[6], c1.z, y);
    h[7] = fmaf(h[7], q[7], u * b1.w); y = fmaf(h[7], c1.w, y);
    yk[(ptrdiff_t)j * sstep] = y;
  }
}

__global__ __launch_bounds__(128) void k_scan(
    const float* __restrict__ xc, const float* __restrict__ xdbl,
    const float* __restrict__ dt_w, const float* __restrict__ dt_b,
    const float* __restrict__ Alogs, const float* __restrict__ Ds,
    float* __restrict__ aggP, float* __restrict__ aggH,
    float* __restrict__ incH, int* __restrict__ flags,
    float* __restrict__ y0, float* __restrict__ y1,
    float* __restrict__ y2, float* __restrict__ y3) {
  const int s = blockIdx.x;               // 0..127 (fastest dispatch dim)
  const int k = blockIdx.y, mb = blockIdx.z;
  const int m = mb >> 2, mbk = mb * 4 + k;
  const int d = threadIdx.x;              // 0..127
  const int bidx = mbk * SEG + s;
  __shared__ float slds[32 * 24];         // dts/B/C tile (3 KB)
  __shared__ float sdt[32 * 128];         // per-step dt (16 KB)
  __shared__ int sflag;

  const float4* ts = (const float4*)(xdbl + ((size_t)mbk * LL + s * 32) * 24);
  ((float4*)slds)[d] = ts[d];
  if (d < 64) ((float4*)slds)[128 + d] = ts[128 + d];

  float aln2[8]; bool fastp;
  load_aln2(Alogs, m, k, d, aln2, fastp);
  float wreg[8];
  {
    const float4 w0 = *(const float4*)&dt_w[((size_t)mbk * DD + d) * 8];
    const float4 w1 = *(const float4*)&dt_w[((size_t)mbk * DD + d) * 8 + 4];
    wreg[0] = w0.x; wreg[1] = w0.y; wreg[2] = w0.z; wreg[3] = w0.w;
    wreg[4] = w1.x; wreg[5] = w1.y; wreg[6] = w1.z; wreg[7] = w1.w;
  }
  const float bw = dt_b[(size_t)mbk * DD + d];
  const float dsv = Ds[(size_t)m * 512 + k * DD + d];

  int base, step;
  seg32_base_step(k, s, base, step);
  const size_t off0 = (size_t)mb * LL * DD + (size_t)base * DD + d;
  const float* __restrict__ xs0 = xc + off0;
  float* __restrict__ yk = (k == 0 ? y0 : k == 1 ? y1 : k == 2 ? y2 : y3) + off0;
  const ptrdiff_t sstep = (ptrdiff_t)step * DD;
  __syncthreads();

  // ---- loop 1: local scan (seed 0), stash dt ----
  float h[8] = {0.f, 0.f, 0.f, 0.f, 0.f, 0.f, 0.f, 0.f};
  float dtsum = 0.f;
  if (fastp) loop1_<true>(slds, sdt, xs0, sstep, aln2, wreg, bw, h, dtsum, d);
  else       loop1_<false>(slds, sdt, xs0, sstep, aln2, wreg, bw, h, dtsum, d);

  float P[8];
#pragma unroll
  for (int n = 0; n < 8; ++n) P[n] = __builtin_amdgcn_exp2f(aln2[n] * dtsum);

  const size_t sb = ((size_t)bidx << 10) + d * 8;
  float hin[8];
  if (s == 0) {
#pragma unroll
    for (int n = 0; n < 8; ++n) {
      hin[n] = 0.f;
      __hip_atomic_store(&incH[sb + n], h[n], __ATOMIC_RELAXED, __HIP_MEMORY_SCOPE_AGENT);
    }
    __syncthreads();
    if (d == 0) {
      __threadfence();
      __hip_atomic_store(&flags[bidx], 2, __ATOMIC_RELEASE, __HIP_MEMORY_SCOPE_AGENT);
    }
  } else {
    // publish aggregate first so successors are not blocked on us
#pragma unroll
    for (int n = 0; n < 8; ++n) {
      __hip_atomic_store(&aggH[sb + n], h[n], __ATOMIC_RELAXED, __HIP_MEMORY_SCOPE_AGENT);
      __hip_atomic_store(&aggP[sb + n], P[n], __ATOMIC_RELAXED, __HIP_MEMORY_SCOPE_AGENT);
    }
    __syncthreads();
    if (d == 0) {
      __threadfence();
      __hip_atomic_store(&flags[bidx], 1, __ATOMIC_RELEASE, __HIP_MEMORY_SCOPE_AGENT);
    }
    // look-back
    float accP[8], accH[8];
#pragma unroll
    for (int n = 0; n < 8; ++n) { accP[n] = 1.f; accH[n] = 0.f; }
    int j = s - 1;
    for (;;) {
      __syncthreads();
      if (d == 0) {
        int f;
        while ((f = __hip_atomic_load(&flags[mbk * SEG + j], __ATOMIC_ACQUIRE,
                                      __HIP_MEMORY_SCOPE_AGENT)) == 0)
          __builtin_amdgcn_s_sleep(1);
        sflag = f;
      }
      __syncthreads();
      const int f = sflag;
      const size_t pb = ((size_t)(mbk * SEG + j) << 10) + d * 8;
      if (f == 2) {
#pragma unroll
        for (int n = 0; n < 8; ++n) {
          const float Hj = __hip_atomic_load(&incH[pb + n], __ATOMIC_RELAXED,
                                             __HIP_MEMORY_SCOPE_AGENT);
          hin[n] = fmaf(accP[n], Hj, accH[n]);
        }
        break;
      } else {
#pragma unroll
        for (int n = 0; n < 8; ++n) {
          const float hj = __hip_atomic_load(&aggH[pb + n], __ATOMIC_RELAXED,
                                             __HIP_MEMORY_SCOPE_AGENT);
          const float pj = __hip_atomic_load(&aggP[pb + n], __ATOMIC_RELAXED,
                                             __HIP_MEMORY_SCOPE_AGENT);
          accH[n] = fmaf(accP[n], hj, accH[n]);
          accP[n] *= pj;
        }
        --j;
      }
    }
    // publish inclusive
#pragma unroll
    for (int n = 0; n < 8; ++n)
      __hip_atomic_store(&incH[sb + n], fmaf(P[n], hin[n], h[n]),
                         __ATOMIC_RELAXED, __HIP_MEMORY_SCOPE_AGENT);
    __syncthreads();
    if (d == 0) {
      __threadfence();
      __hip_atomic_store(&flags[bidx], 2, __ATOMIC_RELEASE, __HIP_MEMORY_SCOPE_AGENT);
    }
  }

  // ---- loop 2: seeded scan producing y (dt from LDS) ----
  if (fastp) loop2_<true>(slds, sdt, xs0, sstep, aln2, dsv, hin, yk, d);
  else       loop2_<false>(slds, sdt, xs0, sstep, aln2, dsv, hin, yk, d);
}

// ---------------- K6: LN(y0+y1+y2+y3) * silu(z) @ out_w^T -> guided -------
__global__ __launch_bounds__(256) void k_outproj(
    const float* __restrict__ y0, const float* __restrict__ y1,
    const float* __restrict__ y2, const float* __restrict__ y3,
    const float* __restrict__ xz, const float* __restrict__ ln_g,
    const float* __restrict__ ln_b, const float* __restrict__ out_w,
    float* __restrict__ guided) {
  const int lt = blockIdx.x, mb = blockIdx.y;
  const int m = mb >> 2;
  __shared__ float sv[32][132];
  __shared__ float sW[64][68];
  __shared__ float smr[32][2];
  __shared__ float sg[128], sb[128];
  const int tid = threadIdx.x;
  const size_t yoff = ((size_t)mb * LL + lt * 32) * DD;
  const float4* p0 = (const float4*)(y0 + yoff);
  const float4* p1 = (const float4*)(y1 + yoff);
  const float4* p2 = (const float4*)(y2 + yoff);
  const float4* p3 = (const float4*)(y3 + yoff);
  float4 ya[4], yb[4], yc4[4], yd4[4];
#pragma unroll
  for (int t = 0; t < 4; ++t) {
    ya[t] = p0[tid + t * 256]; yb[t] = p1[tid + t * 256];
    yc4[t] = p2[tid + t * 256]; yd4[t] = p3[tid + t * 256];
  }
  const int zc = tid >> 1, zh = tid & 1;
  const float4* zsrc = (const float4*)(xz + ((size_t)mb * 256 + 128 + zc) * LL + lt * 32 + zh * 16);
  float4 zv[4];
#pragma unroll
  for (int t = 0; t < 4; ++t) zv[t] = zsrc[t];
  const float* __restrict__ Wp = out_w + (size_t)m * DD * DD;
  float4 wpre[4];
#pragma unroll
  for (int t = 0; t < 4; ++t) {
    const int idx = tid + t * 256;
    wpre[t] = *(const float4*)&Wp[(size_t)(idx >> 4) * DD + ((idx & 15) << 2)];
  }
  if (tid < 128) { sg[tid] = ln_g[m * DD + tid]; sb[tid] = ln_b[m * DD + tid]; }
#pragma unroll
  for (int t = 0; t < 4; ++t) {
    const int idx = tid + t * 256;
    float4 v;
    v.x = (ya[t].x + yb[t].x) + (yc4[t].x + yd4[t].x);
    v.y = (ya[t].y + yb[t].y) + (yc4[t].y + yd4[t].y);
    v.z = (ya[t].z + yb[t].z) + (yc4[t].z + yd4[t].z);
    v.w = (ya[t].w + yb[t].w) + (yc4[t].w + yd4[t].w);
    *(float4*)&sv[idx >> 5][(idx & 31) << 2] = v;
  }
  __syncthreads();
  {
    const int l = tid >> 3, q = tid & 7;
    float s = 0.f, s2 = 0.f;
#pragma unroll
    for (int d0 = 0; d0 < 16; d0 += 4) {
      const float4 v = *(const float4*)&sv[l][q * 16 + d0];
      s += v.x + v.y + v.z + v.w;
      s2 += v.x * v.x + v.y * v.y + v.z * v.z + v.w * v.w;
    }
    s = dpp_add_<0xB1>(s); s = dpp_add_<0x4E>(s); s = dpp_add_<0x141>(s);
    s2 = dpp_add_<0xB1>(s2); s2 = dpp_add_<0x4E>(s2); s2 = dpp_add_<0x141>(s2);
    if (q == 0) {
      const float mean = s * (1.f / 128.f);
      smr[l][0] = mean;
      smr[l][1] = rsqrtf(fmaf(s2, 1.f / 128.f, -mean * mean) + 1e-5f);
    }
  }
  __syncthreads();
  {
    const float g = sg[zc], bb = sb[zc];
    const float* zf = (const float*)zv;
#pragma unroll
    for (int i2 = 0; i2 < 16; ++i2) {
      const int l = zh * 16 + i2;
      const float v = fmaf((sv[l][zc] - smr[l][0]) * smr[l][1], g, bb);
      sv[l][zc] = v * silu_(zf[i2]);
    }
  }
  const int tc = tid & 15, tl = tid >> 4;
  float* __restrict__ dst = guided + ((size_t)mb * LL + lt * 32) * DD;
#pragma unroll
  for (int jb = 0; jb < 2; ++jb) {
    float acc[4][2] = {};
#pragma unroll
    for (int db = 0; db < 2; ++db) {
      __syncthreads();
#pragma unroll
      for (int t = 0; t < 4; ++t) {
        const int idx = tid + t * 256;
        *(float4*)&sW[idx >> 4][(idx & 15) << 2] = wpre[t];
      }
      const int ph = jb * 2 + db + 1;
      if (ph < 4) {
        const int jb2 = ph >> 1, db2 = ph & 1;
#pragma unroll
        for (int t = 0; t < 4; ++t) {
          const int idx = tid + t * 256;
          wpre[t] = *(const float4*)&Wp[(size_t)(jb2 * 64 + (idx >> 4)) * DD + db2 * 64 + ((idx & 15) << 2)];
        }
      }
      __syncthreads();
#pragma unroll 4
      for (int d0 = 0; d0 < 64; d0 += 4) {
        float4 av[2], wv[4];
#pragma unroll
        for (int q = 0; q < 2; ++q) av[q] = *(const float4*)&sv[tl * 2 + q][db * 64 + d0];
#pragma unroll
        for (int j = 0; j < 4; ++j) wv[j] = *(const float4*)&sW[tc + 16 * j][d0];
#pragma unroll
        for (int j = 0; j < 4; ++j)
#pragma unroll
          for (int q = 0; q < 2; ++q)
            acc[j][q] += av[q].x * wv[j].x + av[q].y * wv[j].y + av[q].z * wv[j].z + av[q].w * wv[j].w;
      }
    }
#pragma unroll
    for (int j = 0; j < 4; ++j)
#pragma unroll
      for (int q = 0; q < 2; ++q)
        dst[(size_t)(tl * 2 + q) * DD + jb * 64 + tc + 16 * j] = acc[j][q];
  }
}

// ---------------- K7: enhance (LN -> GEMM -> +bias -> GELU -> +residual) --
__global__ __launch_bounds__(256) void k_enhance(
    const float* __restrict__ guided, const float* __restrict__ eg,
    const float* __restrict__ ebv, const float* __restrict__ ew,
    const float* __restrict__ ebias, const float* __restrict__ sar,
    const float* __restrict__ opt, float* __restrict__ outp) {
  const int lt = blockIdx.x, ib = blockIdx.y;
  const int i = ib >> 2, b = ib & 3;
  __shared__ float sv[32][132];
  __shared__ float sW[64][68];
  __shared__ float smr[32][2];
  __shared__ float sg[128], sb2[128], sbias[128];
  const int tid = threadIdx.x;
  const float4* gsrc =
      (const float4*)(guided + (((size_t)(1 - i) * 4 + b) * LL + lt * 32) * DD);
  float4 gv[4];
#pragma unroll
  for (int t = 0; t < 4; ++t) gv[t] = gsrc[tid + t * 256];
  const float* __restrict__ Wp = ew + (size_t)i * DD * DD;
  float4 wpre[4];
#pragma unroll
  for (int t = 0; t < 4; ++t) {
    const int idx = tid + t * 256;
    wpre[t] = *(const float4*)&Wp[(size_t)(idx >> 4) * DD + ((idx & 15) << 2)];
  }
  if (tid < 128) {
    sg[tid] = eg[i * DD + tid];
    sb2[tid] = ebv[i * DD + tid];
    sbias[tid] = ebias[i * DD + tid];
  }
#pragma unroll
  for (int t = 0; t < 4; ++t) {
    const int idx = tid + t * 256;
    *(float4*)&sv[idx >> 5][(idx & 31) << 2] = gv[t];
  }
  __syncthreads();
  {
    const int l = tid >> 3, q = tid & 7;
    float s = 0.f, s2 = 0.f;
#pragma unroll
    for (int d0 = 0; d0 < 16; d0 += 4) {
      const float4 v = *(const float4*)&sv[l][q * 16 + d0];
      s += v.x + v.y + v.z + v.w;
      s2 += v.x * v.x + v.y * v.y + v.z * v.z + v.w * v.w;
    }
    s = dpp_add_<0xB1>(s); s = dpp_add_<0x4E>(s); s = dpp_add_<0x141>(s);
    s2 = dpp_add_<0xB1>(s2); s2 = dpp_add_<0x4E>(s2); s2 = dpp_add_<0x141>(s2);
    if (q == 0) {
      const float mean = s * (1.f / 128.f);
      smr[l][0] = mean;
      smr[l][1] = rsqrtf(fmaf(s2, 1.f / 128.f, -mean * mean) + 1e-5f);
    }
  }
  __syncthreads();
  {
    const int c = tid >> 1, half = tid & 1;
    const float g = sg[c], bb = sb2[c];
#pragma unroll
    for (int i2 = 0; i2 < 16; ++i2) {
      const int l = half * 16 + i2;
      sv[l][c] = fmaf((sv[l][c] - smr[l][0]) * smr[l][1], g, bb);
    }
  }
  const int tc = tid & 15, tl = tid >> 4;
  const float* __restrict__ resid = (i == 0 ? sar : opt) + ((size_t)b * LL + lt * 32) * DD;
  float* __restrict__ dst = outp + (size_t)i * (4 * LL * DD) + ((size_t)b * LL + lt * 32) * DD;
  float rv[16];
#pragma unroll
  for (int jb = 0; jb < 2; ++jb)
#pragma unroll
    for (int j = 0; j < 4; ++j)
#pragma unroll
      for (int q = 0; q < 2; ++q)
        rv[jb * 8 + j * 2 + q] = resid[(size_t)(tl * 2 + q) * DD + jb * 64 + tc + 16 * j];
  float accA[4][2] = {}, accB[4][2] = {};
#pragma unroll
  for (int jb = 0; jb < 2; ++jb) {
#pragma unroll
    for (int db = 0; db < 2; ++db) {
      __syncthreads();
#pragma unroll
      for (int t = 0; t < 4; ++t) {
        const int idx = tid + t * 256;
        *(float4*)&sW[idx >> 4][(idx & 15) << 2] = wpre[t];
      }
      const int ph = jb * 2 + db + 1;
      if (ph < 4) {
        const int jb2 = ph >> 1, db2 = ph & 1;
#pragma unroll
        for (int t = 0; t < 4; ++t) {
          const int idx = tid + t * 256;
          wpre[t] = *(const float4*)&Wp[(size_t)(jb2 * 64 + (idx >> 4)) * DD + db2 * 64 + ((idx & 15) << 2)];
        }
      }
      __syncthreads();
      float (*acc)[2] = (jb == 0) ? accA : accB;
#pragma unroll 4
      for (int d0 = 0; d0 < 64; d0 += 4) {
        float4 av[2], wv[4];
#pragma unroll
        for (int q = 0; q < 2; ++q) av[q] = *(const float4*)&sv[tl * 2 + q][db * 64 + d0];
#pragma unroll
        for (int j = 0; j < 4; ++j) wv[j] = *(const float4*)&sW[tc + 16 * j][d0];
#pragma unroll
        for (int j = 0; j < 4; ++j)
#pragma unroll
          for (int q = 0; q < 2; ++q)
            acc[j][q] += av[q].x * wv[j].x + av[q].y * wv[j].y + av[q].z * wv[j].z + av[q].w * wv[j].w;
      }
    }
  }
#pragma unroll
  for (int jb = 0; jb < 2; ++jb)
#pragma unroll
    for (int j = 0; j < 4; ++j)
#pragma unroll
      for (int q = 0; q < 2; ++q) {
        const int col = jb * 64 + tc + 16 * j;
        const float u = ((jb == 0) ? accA[j][q] : accB[j][q]) + sbias[col];
        dst[(size_t)(tl * 2 + q) * DD + col] = rv[jb * 8 + j * 2 + q] + gelu_(u);
      }
}

extern "C" void kernel_launch(void* const* d_in, const int* in_sizes, int n_in,
                              void* d_out, int out_size, void* d_ws, size_t ws_size,
                              hipStream_t stream) {
  (void)in_sizes; (void)n_in; (void)out_size; (void)ws_size;
  const float* sar    = (const float*)d_in[0];
  const float* opt    = (const float*)d_in[1];
  const float* in_w   = (const float*)d_in[2];
  const float* conv_w = (const float*)d_in[3];
  const float* conv_b = (const float*)d_in[4];
  const float* xproj_w= (const float*)d_in[5];
  const float* dt_w   = (const float*)d_in[6];
  const float* dt_b   = (const float*)d_in[7];
  const float* Alogs  = (const float*)d_in[8];
  const float* Ds     = (const float*)d_in[9];
  const float* ln_g   = (const float*)d_in[10];
  const float* ln_b   = (const float*)d_in[11];
  const float* out_w  = (const float*)d_in[12];
  const float* eg     = (const float*)d_in[13];
  const float* eb     = (const float*)d_in[14];
  const float* ew     = (const float*)d_in[15];
  const float* ebias  = (const float*)d_in[16];

  float* ws     = (float*)d_ws;
  float* xz     = ws;                  // 8,388,608
  float* xc     = xz + 8388608;        // 4,194,304
  float* xdbl   = xc + 4194304;        // 3,145,728
  float* y0b    = xdbl + 3145728;      // 4,194,304
  float* y1b    = y0b + 4194304;       // 4,194,304
  float* y2b    = y1b + 4194304;       // 4,194,304
  float* y3b    = y2b + 4194304;       // 4,194,304
  float* guided = y3b + 4194304;       // 4,194,304
  float* aggPb  = guided + 4194304;    // 4,194,304
  float* aggHb  = aggPb + 4194304;     // 4,194,304
  float* incHb  = aggHb + 4194304;     // 4,194,304
  int*   flags  = (int*)(incHb + 4194304);   // 4096 ints
  float* outf   = (float*)d_out;

  hipMemsetAsync(flags, 0, 4096 * sizeof(int), stream);
  k_inproj <<<dim3(64, 4, 8), 256, 0, stream>>>(sar, opt, in_w, xz);
  k_conv   <<<dim3(4, 16, 8), 256, 0, stream>>>(xz, conv_w, conv_b, xc);
  k_xproj  <<<dim3(64, 4, 8), 256, 0, stream>>>(xc, xproj_w, xdbl);
  k_scan   <<<dim3(128, 4, 8), 128, 0, stream>>>(xc, xdbl, dt_w, dt_b, Alogs, Ds,
                                                 aggPb, aggHb, incHb, flags,
                                                 y0b, y1b, y2b, y3b);
  k_outproj<<<dim3(128, 8), 256, 0, stream>>>(y0b, y1b, y2b, y3b, xz, ln_g, ln_b, out_w, guided);
  k_enhance<<<dim3(128, 8), 256, 0, stream>>>(guided, eg, eb, ew, ebias, sar, opt, outf);
}

// Round 10
// 265.433 us; speedup vs baseline: 5.4969x; 5.4969x over previous
//
#include <hip/hip_runtime.h>
#include <hip/hip_bf16.h>
#include <math.h>

#define DEV __device__ __forceinline__

static constexpr int LL = 4096;   // H*W
static constexpr int DD = 128;    // hidden
static constexpr int SEG = 128;   // segments per scan (32 positions each)
static constexpr float LOG2E = 1.4426950408889634f;
static constexpr float LN2 = 0.6931471805599453f;

DEV float silu_(float x) { return x / (1.f + __expf(-x)); }
// A&S 7.1.26 erf approximation, |err| <= 1.5e-7
DEV float erf_(float x) {
  const float ax = fabsf(x);
  const float t = 1.f / fmaf(0.3275911f, ax, 1.f);
  float p = fmaf(1.061405429f, t, -1.453152027f);
  p = fmaf(p, t, 1.421413741f);
  p = fmaf(p, t, -0.284496736f);
  p = fmaf(p, t, 0.254829592f);
  p = p * t;
  const float r = 1.f - p * __expf(-ax * ax);
  return x < 0.f ? -r : r;
}
DEV float gelu_(float x) { return 0.5f * x * (1.f + erf_(x * 0.7071067811865475f)); }
DEV float sp_(float x) {
  const float t = __builtin_amdgcn_exp2f(-fabsf(x) * LOG2E);
  return fmaxf(x, 0.f) + LN2 * __builtin_amdgcn_logf(1.f + t);
}

template <int CTRL>
DEV float dpp_add_(float x) {
  int y = __builtin_amdgcn_update_dpp(0, __float_as_int(x), CTRL, 0xF, 0xF, true);
  return x + __int_as_float(y);
}

// 64-position tiles (used by x_proj): tile s of direction k
DEV void seg_base_step(int k, int s, int& base, int& step) {
  if (k == 0)      { base = s * 64;        step = 1;   }
  else if (k == 1) { base = s;             step = 64;  }
  else if (k == 2) { base = 4095 - s * 64; step = -1;  }
  else             { base = 4095 - s;      step = -64; }
}

// ---------------- K1: in_proj: xz[m][b][c][l] = x @ in_w^T (c-major out) ----
__global__ __launch_bounds__(256) void k_inproj(
    const float* __restrict__ sar, const float* __restrict__ opt,
    const float* __restrict__ in_w, float* __restrict__ xz) {
  const int lt = blockIdx.x, ct = blockIdx.y, mb = blockIdx.z;
  const int m = mb >> 2;
  const float* __restrict__ x = (m == 0 ? opt : sar) + (size_t)(mb & 3) * (LL * DD);
  const float* __restrict__ W = in_w + (size_t)m * 256 * DD;
  __shared__ float sA[64][68];
  __shared__ float sW[64][68];
  const int tid = threadIdx.x;
  const int tc = tid & 15, tl = tid >> 4;
  float acc[4][4] = {};
  for (int db = 0; db < 2; ++db) {
    __syncthreads();
    for (int idx = tid; idx < 64 * 16; idx += 256) {
      const int r = idx >> 4, d4 = (idx & 15) << 2;
      *(float4*)&sA[r][d4] = *(const float4*)&x[(size_t)(lt * 64 + r) * DD + db * 64 + d4];
      *(float4*)&sW[r][d4] = *(const float4*)&W[(size_t)(ct * 64 + r) * DD + db * 64 + d4];
    }
    __syncthreads();
#pragma unroll 4
    for (int d = 0; d < 64; d += 4) {
      float4 a[4], w[4];
#pragma unroll
      for (int q = 0; q < 4; ++q) a[q] = *(const float4*)&sA[tl * 4 + q][d];
#pragma unroll
      for (int j = 0; j < 4; ++j) w[j] = *(const float4*)&sW[tc + 16 * j][d];
#pragma unroll
      for (int j = 0; j < 4; ++j)
#pragma unroll
        for (int q = 0; q < 4; ++q)
          acc[j][q] += a[q].x * w[j].x + a[q].y * w[j].y + a[q].z * w[j].z + a[q].w * w[j].w;
    }
  }
  float* __restrict__ dst = xz + ((size_t)mb * 256 + ct * 64) * LL + lt * 64;
#pragma unroll
  for (int j = 0; j < 4; ++j) {
    float4 v = make_float4(acc[j][0], acc[j][1], acc[j][2], acc[j][3]);
    *(float4*)&dst[(size_t)(tc + 16 * j) * LL + tl * 4] = v;
  }
}

// ---------------- K2: depthwise 3x3 SAME conv + bias + SiLU ---------------
__global__ __launch_bounds__(256) void k_conv(
    const float* __restrict__ xz, const float* __restrict__ conv_w,
    const float* __restrict__ conv_b, float* __restrict__ xc) {
  const int ht = blockIdx.x, dg = blockIdx.y, mb = blockIdx.z;
  const int m = mb >> 2;
  __shared__ float sIn[8][18][66];
  __shared__ float sOut[1024][8];
  const float* __restrict__ src = xz + ((size_t)mb * 256 + dg * 8) * LL;
  const int tid = threadIdx.x;
  for (int idx = tid; idx < 8 * 18 * 66; idx += 256) {
    const int dd = idx / (18 * 66);
    const int rem = idx - dd * (18 * 66);
    const int hh = rem / 66, ww = rem - hh * 66;
    const int h = ht * 16 + hh - 1, w = ww - 1;
    float v = 0.f;
    if (h >= 0 && h < 64 && w >= 0 && w < 64) v = src[(size_t)dd * LL + h * 64 + w];
    sIn[dd][hh][ww] = v;
  }
  __syncthreads();
  const int dd = tid & 7, wv = tid >> 3;
  const int dch = dg * 8 + dd;
  float wk[9];
#pragma unroll
  for (int t = 0; t < 9; ++t) wk[t] = conv_w[((size_t)m * DD + dch) * 9 + t];
  const float bias = conv_b[m * DD + dch];
  for (int hh = 0; hh < 16; ++hh) {
#pragma unroll
    for (int wh = 0; wh < 2; ++wh) {
      const int w = wv + wh * 32;
      float s = bias;
#pragma unroll
      for (int kh = 0; kh < 3; ++kh)
#pragma unroll
        for (int kw = 0; kw < 3; ++kw)
          s = fmaf(sIn[dd][hh + kh][w + kw], wk[kh * 3 + kw], s);
      sOut[hh * 64 + w][dd] = silu_(s);
    }
  }
  __syncthreads();
  float* __restrict__ dst = xc + (size_t)mb * LL * DD + dg * 8;
#pragma unroll
  for (int r = 0; r < 4; ++r) {
    const int pos = tid + r * 256;
    const int l = ht * 1024 + pos;
    *(float4*)&dst[(size_t)l * DD + 0] = *(const float4*)&sOut[pos][0];
    *(float4*)&dst[(size_t)l * DD + 4] = *(const float4*)&sOut[pos][4];
  }
}

// ---------------- K3: x_proj -> xdbl[mbk][l][24]  (l-major, contiguous) ---
__global__ __launch_bounds__(256) void k_xproj(
    const float* __restrict__ xc, const float* __restrict__ xproj_w,
    float* __restrict__ xdbl) {
  const int lt = blockIdx.x, k = blockIdx.y, mb = blockIdx.z;
  const int m = mb >> 2, mbk = mb * 4 + k;
  __shared__ float sX[64][132];
  __shared__ float sW[24][132];
  const int tid = threadIdx.x;
  const float* __restrict__ src = xc + (size_t)mb * LL * DD;
  int base, step;
  seg_base_step(k, lt, base, step);
  for (int idx = tid; idx < 64 * 32; idx += 256) {
    const int l = idx >> 5, d4 = (idx & 31) << 2;
    *(float4*)&sX[l][d4] = *(const float4*)&src[(size_t)(base + l * step) * DD + d4];
  }
  const float* __restrict__ Wsrc = xproj_w + ((size_t)m * 4 + k) * 24 * DD;
  for (int idx = tid; idx < 24 * 32; idx += 256) {
    const int r = idx >> 5, d4 = (idx & 31) << 2;
    *(float4*)&sW[r][d4] = *(const float4*)&Wsrc[(size_t)r * DD + d4];
  }
  __syncthreads();
  const int l = tid >> 2, cg = tid & 3;
  float acc[6] = {};
#pragma unroll 8
  for (int d = 0; d < 128; d += 4) {
    const float4 xv = *(const float4*)&sX[l][d];
#pragma unroll
    for (int j = 0; j < 6; ++j) {
      const float4 wv = *(const float4*)&sW[cg * 6 + j][d];
      acc[j] += xv.x * wv.x + xv.y * wv.y + xv.z * wv.z + xv.w * wv.w;
    }
  }
  float* __restrict__ dst = xdbl + ((size_t)mbk * LL + lt * 64 + l) * 24 + cg * 6;
#pragma unroll
  for (int j = 0; j < 6; ++j) dst[j] = acc[j];
}

// ============== dual-chain segmented selective scan (SEGL=32) =============
// Block (s, p, mb): one 32-position physical strip (row for p=0, col for
// p=1). Chain A = direction p, segment s (walks strip forward); chain B =
// direction p+2, segment 127-s (walks strip backward). The x strip is staged
// once in LDS and shared by both chains; the two recurrences interleave in
// one loop for 2x ILP.

DEV void load_aln2(const float* __restrict__ Alogs, int m, int k, int d,
                   float* __restrict__ aln2, bool& fastp) {
  const float4 a0 = *(const float4*)&Alogs[((size_t)m * 512 + k * DD + d) * 8];
  const float4 a1 = *(const float4*)&Alogs[((size_t)m * 512 + k * DD + d) * 8 + 4];
  aln2[0] = -__expf(a0.x) * LOG2E; aln2[1] = -__expf(a0.y) * LOG2E;
  aln2[2] = -__expf(a0.z) * LOG2E; aln2[3] = -__expf(a0.w) * LOG2E;
  aln2[4] = -__expf(a1.x) * LOG2E; aln2[5] = -__expf(a1.y) * LOG2E;
  aln2[6] = -__expf(a1.z) * LOG2E; aln2[7] = -__expf(a1.w) * LOG2E;
  fastp = true;
#pragma unroll
  for (int n = 1; n < 8; ++n)
    fastp = fastp && (fabsf(aln2[n] - (float)(n + 1) * aln2[0]) <=
                      1e-4f * fabsf(aln2[n]) + 1e-12f);
}

DEV void load_w8(const float* __restrict__ dt_w, int mbk, int d,
                 float* __restrict__ wreg) {
  const float4 w0 = *(const float4*)&dt_w[((size_t)mbk * DD + d) * 8];
  const float4 w1 = *(const float4*)&dt_w[((size_t)mbk * DD + d) * 8 + 4];
  wreg[0] = w0.x; wreg[1] = w0.y; wreg[2] = w0.z; wreg[3] = w0.w;
  wreg[4] = w1.x; wreg[5] = w1.y; wreg[6] = w1.z; wreg[7] = w1.w;
}

template <bool FAST>
DEV void qpow_(float dt, const float* __restrict__ aln2, float* __restrict__ q) {
  if constexpr (FAST) {
    q[0] = __builtin_amdgcn_exp2f(dt * aln2[0]);
    q[1] = q[0] * q[0]; q[2] = q[1] * q[0]; q[3] = q[1] * q[1];
    q[4] = q[3] * q[0]; q[5] = q[3] * q[1]; q[6] = q[3] * q[2]; q[7] = q[3] * q[3];
  } else {
#pragma unroll
    for (int n = 0; n < 8; ++n) q[n] = __builtin_amdgcn_exp2f(dt * aln2[n]);
  }
}

DEV float dt_of_(const float* __restrict__ slds, int j,
                 const float* __restrict__ w, float bw) {
  const float4 t0 = *(const float4*)&slds[j * 24 + 0];
  const float4 t1 = *(const float4*)&slds[j * 24 + 4];
  float s = bw;
  s = fmaf(t0.x, w[0], s); s = fmaf(t0.y, w[1], s);
  s = fmaf(t0.z, w[2], s); s = fmaf(t0.w, w[3], s);
  s = fmaf(t1.x, w[4], s); s = fmaf(t1.y, w[5], s);
  s = fmaf(t1.z, w[6], s); s = fmaf(t1.w, w[7], s);
  return sp_(s);
}

template <bool FAST>
DEV void hstep_(const float* __restrict__ slds, int j, float dt, float x,
                const float* __restrict__ aln2, float* __restrict__ h) {
  const float u = dt * x;
  float q[8];
  qpow_<FAST>(dt, aln2, q);
  const float4 b0 = *(const float4*)&slds[j * 24 + 8];
  const float4 b1 = *(const float4*)&slds[j * 24 + 12];
  h[0] = fmaf(h[0], q[0], u * b0.x);
  h[1] = fmaf(h[1], q[1], u * b0.y);
  h[2] = fmaf(h[2], q[2], u * b0.z);
  h[3] = fmaf(h[3], q[3], u * b0.w);
  h[4] = fmaf(h[4], q[4], u * b1.x);
  h[5] = fmaf(h[5], q[5], u * b1.y);
  h[6] = fmaf(h[6], q[6], u * b1.z);
  h[7] = fmaf(h[7], q[7], u * b1.w);
}

template <bool FAST>
DEV float ystep_(const float* __restrict__ slds, int j, float dt, float x,
                 const float* __restrict__ aln2, float dsv,
                 float* __restrict__ h) {
  const float u = dt * x;
  float q[8];
  qpow_<FAST>(dt, aln2, q);
  const float4 b0 = *(const float4*)&slds[j * 24 + 8];
  const float4 b1 = *(const float4*)&slds[j * 24 + 12];
  const float4 c0 = *(const float4*)&slds[j * 24 + 16];
  const float4 c1 = *(const float4*)&slds[j * 24 + 20];
  float y = dsv * x;
  h[0] = fmaf(h[0], q[0], u * b0.x); y = fmaf(h[0], c0.x, y);
  h[1] = fmaf(h[1], q[1], u * b0.y); y = fmaf(h[1], c0.y, y);
  h[2] = fmaf(h[2], q[2], u * b0.z); y = fmaf(h[2], c0.z, y);
  h[3] = fmaf(h[3], q[3], u * b0.w); y = fmaf(h[3], c0.w, y);
  h[4] = fmaf(h[4], q[4], u * b1.x); y = fmaf(h[4], c1.x, y);
  h[5] = fmaf(h[5], q[5], u * b1.y); y = fmaf(h[5], c1.y, y);
  h[6] = fmaf(h[6], q[6], u * b1.z); y = fmaf(h[6], c1.z, y);
  h[7] = fmaf(h[7], q[7], u * b1.w); y = fmaf(h[7], c1.w, y);
  return y;
}

// ---- pass 1: dual-chain local scan (h0=0) -> h_end, P --------------------
template <bool FAST>
DEV void loop1d_(const float* __restrict__ sldsA, const float* __restrict__ sldsB,
                 const float* __restrict__ sx, int d,
                 const float* __restrict__ aln2A, const float* __restrict__ aln2B,
                 const float* __restrict__ wA, const float* __restrict__ wB,
                 float bwA, float bwB, float* __restrict__ hA,
                 float* __restrict__ hB, float& dtsA, float& dtsB) {
#pragma unroll 8
  for (int j = 0; j < 32; ++j) {
    const float xA = sx[j * 128 + d];
    const float xB = sx[(31 - j) * 128 + d];
    const float dtA = dt_of_(sldsA, j, wA, bwA);
    const float dtB = dt_of_(sldsB, j, wB, bwB);
    dtsA += dtA; dtsB += dtB;
    hstep_<FAST>(sldsA, j, dtA, xA, aln2A, hA);
    hstep_<FAST>(sldsB, j, dtB, xB, aln2B, hB);
  }
}

__global__ __launch_bounds__(128) void k_scan1(
    const float* __restrict__ xc, const float* __restrict__ xdbl,
    const float* __restrict__ dt_w, const float* __restrict__ dt_b,
    const float* __restrict__ Alogs, float* __restrict__ hend,
    float* __restrict__ Pseg) {
  const int s = blockIdx.x, p = blockIdx.y, mb = blockIdx.z;
  const int m = mb >> 2;
  const int kA = p, kB = p + 2;
  const int sA = s, sB = 127 - s;
  const int mbkA = mb * 4 + kA, mbkB = mb * 4 + kB;
  const int d = threadIdx.x;
  __shared__ float sldsA[32 * 24], sldsB[32 * 24];  // 3 KB each
  __shared__ float sx[32 * 128];                    // 16 KB

  const float4* tA = (const float4*)(xdbl + ((size_t)mbkA * LL + sA * 32) * 24);
  const float4* tB = (const float4*)(xdbl + ((size_t)mbkB * LL + sB * 32) * 24);
  ((float4*)sldsA)[d] = tA[d];
  if (d < 64) ((float4*)sldsA)[128 + d] = tA[128 + d];
  ((float4*)sldsB)[d] = tB[d];
  if (d < 64) ((float4*)sldsB)[128 + d] = tB[128 + d];

  const int base0 = (p == 0) ? s * 32 : ((s & 1) * 32) * 64 + (s >> 1);
  const int stepPos = (p == 0) ? 1 : 64;
  const float* __restrict__ xsrc = xc + (size_t)mb * LL * DD;
#pragma unroll
  for (int t = 0; t < 8; ++t) {
    const int idx = d + t * 128;
    const int r = idx >> 5, c4 = (idx & 31) << 2;
    ((float4*)sx)[idx] = *(const float4*)&xsrc[(size_t)(base0 + r * stepPos) * DD + c4];
  }

  float aln2A[8], aln2B[8]; bool fA, fB;
  load_aln2(Alogs, m, kA, d, aln2A, fA);
  load_aln2(Alogs, m, kB, d, aln2B, fB);
  float wA[8], wB[8];
  load_w8(dt_w, mbkA, d, wA);
  load_w8(dt_w, mbkB, d, wB);
  const float bwA = dt_b[(size_t)mbkA * DD + d];
  const float bwB = dt_b[(size_t)mbkB * DD + d];
  __syncthreads();

  float hA[8] = {0, 0, 0, 0, 0, 0, 0, 0};
  float hB[8] = {0, 0, 0, 0, 0, 0, 0, 0};
  float dtsA = 0.f, dtsB = 0.f;
  if (fA && fB)
    loop1d_<true>(sldsA, sldsB, sx, d, aln2A, aln2B, wA, wB, bwA, bwB, hA, hB, dtsA, dtsB);
  else
    loop1d_<false>(sldsA, sldsB, sx, d, aln2A, aln2B, wA, wB, bwA, bwB, hA, hB, dtsA, dtsB);

  {
    float* __restrict__ he = hend + (((size_t)mbkA * SEG + sA) << 10) + d * 8;
    float* __restrict__ pe = Pseg + (((size_t)mbkA * SEG + sA) << 10) + d * 8;
    *(float4*)&he[0] = make_float4(hA[0], hA[1], hA[2], hA[3]);
    *(float4*)&he[4] = make_float4(hA[4], hA[5], hA[6], hA[7]);
    *(float4*)&pe[0] = make_float4(
        __builtin_amdgcn_exp2f(aln2A[0] * dtsA), __builtin_amdgcn_exp2f(aln2A[1] * dtsA),
        __builtin_amdgcn_exp2f(aln2A[2] * dtsA), __builtin_amdgcn_exp2f(aln2A[3] * dtsA));
    *(float4*)&pe[4] = make_float4(
        __builtin_amdgcn_exp2f(aln2A[4] * dtsA), __builtin_amdgcn_exp2f(aln2A[5] * dtsA),
        __builtin_amdgcn_exp2f(aln2A[6] * dtsA), __builtin_amdgcn_exp2f(aln2A[7] * dtsA));
  }
  {
    float* __restrict__ he = hend + (((size_t)mbkB * SEG + sB) << 10) + d * 8;
    float* __restrict__ pe = Pseg + (((size_t)mbkB * SEG + sB) << 10) + d * 8;
    *(float4*)&he[0] = make_float4(hB[0], hB[1], hB[2], hB[3]);
    *(float4*)&he[4] = make_float4(hB[4], hB[5], hB[6], hB[7]);
    *(float4*)&pe[0] = make_float4(
        __builtin_amdgcn_exp2f(aln2B[0] * dtsB), __builtin_amdgcn_exp2f(aln2B[1] * dtsB),
        __builtin_amdgcn_exp2f(aln2B[2] * dtsB), __builtin_amdgcn_exp2f(aln2B[3] * dtsB));
    *(float4*)&pe[4] = make_float4(
        __builtin_amdgcn_exp2f(aln2B[4] * dtsB), __builtin_amdgcn_exp2f(aln2B[5] * dtsB),
        __builtin_amdgcn_exp2f(aln2B[6] * dtsB), __builtin_amdgcn_exp2f(aln2B[7] * dtsB));
  }
}

// ---- pass 2: sequential combine across 128 segments -> h_in --------------
__global__ __launch_bounds__(256) void k_scan2(
    const float* __restrict__ hend, const float* __restrict__ Pseg,
    float* __restrict__ hin) {
  const int gid = blockIdx.x * 256 + threadIdx.x;   // 32768
  const int mbk = gid >> 10, dn = gid & 1023;
  const float* __restrict__ P = Pseg + ((size_t)mbk * SEG << 10) + dn;
  const float* __restrict__ E = hend + ((size_t)mbk * SEG << 10) + dn;
  float* __restrict__ O = hin + ((size_t)mbk * SEG << 10) + dn;
  float h = 0.f;
#pragma unroll
  for (int s = 0; s < SEG; ++s) {
    O[(size_t)s << 10] = h;
    if (s < SEG - 1) h = fmaf(P[(size_t)s << 10], h, E[(size_t)s << 10]);
  }
}

// ---- pass 3: dual-chain seeded scan producing y (plain stores) -----------
template <bool FAST>
DEV void loop3d_(const float* __restrict__ sldsA, const float* __restrict__ sldsB,
                 const float* __restrict__ sx, int d,
                 const float* __restrict__ aln2A, const float* __restrict__ aln2B,
                 const float* __restrict__ wA, const float* __restrict__ wB,
                 float bwA, float bwB, float dsvA, float dsvB,
                 float* __restrict__ hA, float* __restrict__ hB,
                 float* __restrict__ yA, float* __restrict__ yB,
                 ptrdiff_t sstep) {
#pragma unroll 8
  for (int j = 0; j < 32; ++j) {
    const float xA = sx[j * 128 + d];
    const float xB = sx[(31 - j) * 128 + d];
    const float dtA = dt_of_(sldsA, j, wA, bwA);
    const float dtB = dt_of_(sldsB, j, wB, bwB);
    const float vA = ystep_<FAST>(sldsA, j, dtA, xA, aln2A, dsvA, hA);
    const float vB = ystep_<FAST>(sldsB, j, dtB, xB, aln2B, dsvB, hB);
    yA[(ptrdiff_t)j * sstep] = vA;
    yB[(ptrdiff_t)(31 - j) * sstep] = vB;
  }
}

__global__ __launch_bounds__(128) void k_scan3(
    const float* __restrict__ xc, const float* __restrict__ xdbl,
    const float* __restrict__ dt_w, const float* __restrict__ dt_b,
    const float* __restrict__ Alogs, const float* __restrict__ Ds,
    const float* __restrict__ hin, float* __restrict__ y0,
    float* __restrict__ y1, float* __restrict__ y2, float* __restrict__ y3) {
  const int s = blockIdx.x, p = blockIdx.y, mb = blockIdx.z;
  const int m = mb >> 2;
  const int kA = p, kB = p + 2;
  const int sA = s, sB = 127 - s;
  const int mbkA = mb * 4 + kA, mbkB = mb * 4 + kB;
  const int d = threadIdx.x;
  __shared__ float sldsA[32 * 24], sldsB[32 * 24];
  __shared__ float sx[32 * 128];

  const float4* tA = (const float4*)(xdbl + ((size_t)mbkA * LL + sA * 32) * 24);
  const float4* tB = (const float4*)(xdbl + ((size_t)mbkB * LL + sB * 32) * 24);
  ((float4*)sldsA)[d] = tA[d];
  if (d < 64) ((float4*)sldsA)[128 + d] = tA[128 + d];
  ((float4*)sldsB)[d] = tB[d];
  if (d < 64) ((float4*)sldsB)[128 + d] = tB[128 + d];

  const int base0 = (p == 0) ? s * 32 : ((s & 1) * 32) * 64 + (s >> 1);
  const int stepPos = (p == 0) ? 1 : 64;
  const float* __restrict__ xsrc = xc + (size_t)mb * LL * DD;
#pragma unroll
  for (int t = 0; t < 8; ++t) {
    const int idx = d + t * 128;
    const int r = idx >> 5, c4 = (idx & 31) << 2;
    ((float4*)sx)[idx] = *(const float4*)&xsrc[(size_t)(base0 + r * stepPos) * DD + c4];
  }

  float aln2A[8], aln2B[8]; bool fA, fB;
  load_aln2(Alogs, m, kA, d, aln2A, fA);
  load_aln2(Alogs, m, kB, d, aln2B, fB);
  float wA[8], wB[8];
  load_w8(dt_w, mbkA, d, wA);
  load_w8(dt_w, mbkB, d, wB);
  const float bwA = dt_b[(size_t)mbkA * DD + d];
  const float bwB = dt_b[(size_t)mbkB * DD + d];
  const float dsvA = Ds[(size_t)m * 512 + kA * DD + d];
  const float dsvB = Ds[(size_t)m * 512 + kB * DD + d];

  float hA[8], hB[8];
  {
    const float* hp = hin + (((size_t)mbkA * SEG + sA) << 10) + d * 8;
    const float4 h0 = *(const float4*)&hp[0];
    const float4 h1 = *(const float4*)&hp[4];
    hA[0] = h0.x; hA[1] = h0.y; hA[2] = h0.z; hA[3] = h0.w;
    hA[4] = h1.x; hA[5] = h1.y; hA[6] = h1.z; hA[7] = h1.w;
  }
  {
    const float* hp = hin + (((size_t)mbkB * SEG + sB) << 10) + d * 8;
    const float4 h0 = *(const float4*)&hp[0];
    const float4 h1 = *(const float4*)&hp[4];
    hB[0] = h0.x; hB[1] = h0.y; hB[2] = h0.z; hB[3] = h0.w;
    hB[4] = h1.x; hB[5] = h1.y; hB[6] = h1.z; hB[7] = h1.w;
  }

  const size_t off0 = (size_t)mb * LL * DD + (size_t)base0 * DD + d;
  float* __restrict__ yA = (p == 0 ? y0 : y1) + off0;
  float* __restrict__ yB = (p == 0 ? y2 : y3) + off0;
  const ptrdiff_t sstep = (ptrdiff_t)stepPos * DD;
  __syncthreads();

  if (fA && fB)
    loop3d_<true>(sldsA, sldsB, sx, d, aln2A, aln2B, wA, wB, bwA, bwB,
                  dsvA, dsvB, hA, hB, yA, yB, sstep);
  else
    loop3d_<false>(sldsA, sldsB, sx, d, aln2A, aln2B, wA, wB, bwA, bwB,
                   dsvA, dsvB, hA, hB, yA, yB, sstep);
}

// ---------------- K6: LN(y0+y1+y2+y3) * silu(z) @ out_w^T -> guided -------
__global__ __launch_bounds__(256) void k_outproj(
    const float* __restrict__ y0, const float* __restrict__ y1,
    const float* __restrict__ y2, const float* __restrict__ y3,
    const float* __restrict__ xz, const float* __restrict__ ln_g,
    const float* __restrict__ ln_b, const float* __restrict__ out_w,
    float* __restrict__ guided) {
  const int lt = blockIdx.x, mb = blockIdx.y;
  const int m = mb >> 2;
  __shared__ float sv[32][132];
  __shared__ float sW[64][68];
  __shared__ float smr[32][2];
  __shared__ float sg[128], sb[128];
  const int tid = threadIdx.x;
  const size_t yoff = ((size_t)mb * LL + lt * 32) * DD;
  const float4* p0 = (const float4*)(y0 + yoff);
  const float4* p1 = (const float4*)(y1 + yoff);
  const float4* p2 = (const float4*)(y2 + yoff);
  const float4* p3 = (const float4*)(y3 + yoff);
  float4 ya[4], yb[4], yc4[4], yd4[4];
#pragma unroll
  for (int t = 0; t < 4; ++t) {
    ya[t] = p0[tid + t * 256]; yb[t] = p1[tid + t * 256];
    yc4[t] = p2[tid + t * 256]; yd4[t] = p3[tid + t * 256];
  }
  const int zc = tid >> 1, zh = tid & 1;
  const float4* zsrc = (const float4*)(xz + ((size_t)mb * 256 + 128 + zc) * LL + lt * 32 + zh * 16);
  float4 zv[4];
#pragma unroll
  for (int t = 0; t < 4; ++t) zv[t] = zsrc[t];
  const float* __restrict__ Wp = out_w + (size_t)m * DD * DD;
  float4 wpre[4];
#pragma unroll
  for (int t = 0; t < 4; ++t) {
    const int idx = tid + t * 256;
    wpre[t] = *(const float4*)&Wp[(size_t)(idx >> 4) * DD + ((idx & 15) << 2)];
  }
  if (tid < 128) { sg[tid] = ln_g[m * DD + tid]; sb[tid] = ln_b[m * DD + tid]; }
#pragma unroll
  for (int t = 0; t < 4; ++t) {
    const int idx = tid + t * 256;
    float4 v;
    v.x = (ya[t].x + yb[t].x) + (yc4[t].x + yd4[t].x);
    v.y = (ya[t].y + yb[t].y) + (yc4[t].y + yd4[t].y);
    v.z = (ya[t].z + yb[t].z) + (yc4[t].z + yd4[t].z);
    v.w = (ya[t].w + yb[t].w) + (yc4[t].w + yd4[t].w);
    *(float4*)&sv[idx >> 5][(idx & 31) << 2] = v;
  }
  __syncthreads();
  {
    const int l = tid >> 3, q = tid & 7;
    float s = 0.f, s2 = 0.f;
#pragma unroll
    for (int d0 = 0; d0 < 16; d0 += 4) {
      const float4 v = *(const float4*)&sv[l][q * 16 + d0];
      s += v.x + v.y + v.z + v.w;
      s2 += v.x * v.x + v.y * v.y + v.z * v.z + v.w * v.w;
    }
    s = dpp_add_<0xB1>(s); s = dpp_add_<0x4E>(s); s = dpp_add_<0x141>(s);
    s2 = dpp_add_<0xB1>(s2); s2 = dpp_add_<0x4E>(s2); s2 = dpp_add_<0x141>(s2);
    if (q == 0) {
      const float mean = s * (1.f / 128.f);
      smr[l][0] = mean;
      smr[l][1] = rsqrtf(fmaf(s2, 1.f / 128.f, -mean * mean) + 1e-5f);
    }
  }
  __syncthreads();
  {
    const float g = sg[zc], bb = sb[zc];
    const float* zf = (const float*)zv;
#pragma unroll
    for (int i2 = 0; i2 < 16; ++i2) {
      const int l = zh * 16 + i2;
      const float v = fmaf((sv[l][zc] - smr[l][0]) * smr[l][1], g, bb);
      sv[l][zc] = v * silu_(zf[i2]);
    }
  }
  const int tc = tid & 15, tl = tid >> 4;
  float* __restrict__ dst = guided + ((size_t)mb * LL + lt * 32) * DD;
#pragma unroll
  for (int jb = 0; jb < 2; ++jb) {
    float acc[4][2] = {};
#pragma unroll
    for (int db = 0; db < 2; ++db) {
      __syncthreads();
#pragma unroll
      for (int t = 0; t < 4; ++t) {
        const int idx = tid + t * 256;
        *(float4*)&sW[idx >> 4][(idx & 15) << 2] = wpre[t];
      }
      const int ph = jb * 2 + db + 1;
      if (ph < 4) {
        const int jb2 = ph >> 1, db2 = ph & 1;
#pragma unroll
        for (int t = 0; t < 4; ++t) {
          const int idx = tid + t * 256;
          wpre[t] = *(const float4*)&Wp[(size_t)(jb2 * 64 + (idx >> 4)) * DD + db2 * 64 + ((idx & 15) << 2)];
        }
      }
      __syncthreads();
#pragma unroll 4
      for (int d0 = 0; d0 < 64; d0 += 4) {
        float4 av[2], wv[4];
#pragma unroll
        for (int q = 0; q < 2; ++q) av[q] = *(const float4*)&sv[tl * 2 + q][db * 64 + d0];
#pragma unroll
        for (int j = 0; j < 4; ++j) wv[j] = *(const float4*)&sW[tc + 16 * j][d0];
#pragma unroll
        for (int j = 0; j < 4; ++j)
#pragma unroll
          for (int q = 0; q < 2; ++q)
            acc[j][q] += av[q].x * wv[j].x + av[q].y * wv[j].y + av[q].z * wv[j].z + av[q].w * wv[j].w;
      }
    }
#pragma unroll
    for (int j = 0; j < 4; ++j)
#pragma unroll
      for (int q = 0; q < 2; ++q)
        dst[(size_t)(tl * 2 + q) * DD + jb * 64 + tc + 16 * j] = acc[j][q];
  }
}

// ---------------- K7: enhance (LN -> GEMM -> +bias -> GELU -> +residual) --
__global__ __launch_bounds__(256) void k_enhance(
    const float* __restrict__ guided, const float* __restrict__ eg,
    const float* __restrict__ ebv, const float* __restrict__ ew,
    const float* __restrict__ ebias, const float* __restrict__ sar,
    const float* __restrict__ opt, float* __restrict__ outp) {
  const int lt = blockIdx.x, ib = blockIdx.y;
  const int i = ib >> 2, b = ib & 3;
  __shared__ float sv[32][132];
  __shared__ float sW[64][68];
  __shared__ float smr[32][2];
  __shared__ float sg[128], sb2[128], sbias[128];
  const int tid = threadIdx.x;
  const float4* gsrc =
      (const float4*)(guided + (((size_t)(1 - i) * 4 + b) * LL + lt * 32) * DD);
  float4 gv[4];
#pragma unroll
  for (int t = 0; t < 4; ++t) gv[t] = gsrc[tid + t * 256];
  const float* __restrict__ Wp = ew + (size_t)i * DD * DD;
  float4 wpre[4];
#pragma unroll
  for (int t = 0; t < 4; ++t) {
    const int idx = tid + t * 256;
    wpre[t] = *(const float4*)&Wp[(size_t)(idx >> 4) * DD + ((idx & 15) << 2)];
  }
  if (tid < 128) {
    sg[tid] = eg[i * DD + tid];
    sb2[tid] = ebv[i * DD + tid];
    sbias[tid] = ebias[i * DD + tid];
  }
#pragma unroll
  for (int t = 0; t < 4; ++t) {
    const int idx = tid + t * 256;
    *(float4*)&sv[idx >> 5][(idx & 31) << 2] = gv[t];
  }
  __syncthreads();
  {
    const int l = tid >> 3, q = tid & 7;
    float s = 0.f, s2 = 0.f;
#pragma unroll
    for (int d0 = 0; d0 < 16; d0 += 4) {
      const float4 v = *(const float4*)&sv[l][q * 16 + d0];
      s += v.x + v.y + v.z + v.w;
      s2 += v.x * v.x + v.y * v.y + v.z * v.z + v.w * v.w;
    }
    s = dpp_add_<0xB1>(s); s = dpp_add_<0x4E>(s); s = dpp_add_<0x141>(s);
    s2 = dpp_add_<0xB1>(s2); s2 = dpp_add_<0x4E>(s2); s2 = dpp_add_<0x141>(s2);
    if (q == 0) {
      const float mean = s * (1.f / 128.f);
      smr[l][0] = mean;
      smr[l][1] = rsqrtf(fmaf(s2, 1.f / 128.f, -mean * mean) + 1e-5f);
    }
  }
  __syncthreads();
  {
    const int c = tid >> 1, half = tid & 1;
    const float g = sg[c], bb = sb2[c];
#pragma unroll
    for (int i2 = 0; i2 < 16; ++i2) {
      const int l = half * 16 + i2;
      sv[l][c] = fmaf((sv[l][c] - smr[l][0]) * smr[l][1], g, bb);
    }
  }
  const int tc = tid & 15, tl = tid >> 4;
  const float* __restrict__ resid = (i == 0 ? sar : opt) + ((size_t)b * LL + lt * 32) * DD;
  float* __restrict__ dst = outp + (size_t)i * (4 * LL * DD) + ((size_t)b * LL + lt * 32) * DD;
  float rv[16];
#pragma unroll
  for (int jb = 0; jb < 2; ++jb)
#pragma unroll
    for (int j = 0; j < 4; ++j)
#pragma unroll
      for (int q = 0; q < 2; ++q)
        rv[jb * 8 + j * 2 + q] = resid[(size_t)(tl * 2 + q) * DD + jb * 64 + tc + 16 * j];
  float accA[4][2] = {}, accB[4][2] = {};
#pragma unroll
  for (int jb = 0; jb < 2; ++jb) {
#pragma unroll
    for (int db = 0; db < 2; ++db) {
      __syncthreads();
#pragma unroll
      for (int t = 0; t < 4; ++t) {
        const int idx = tid + t * 256;
        *(float4*)&sW[idx >> 4][(idx & 15) << 2] = wpre[t];
      }
      const int ph = jb * 2 + db + 1;
      if (ph < 4) {
        const int jb2 = ph >> 1, db2 = ph & 1;
#pragma unroll
        for (int t = 0; t < 4; ++t) {
          const int idx = tid + t * 256;
          wpre[t] = *(const float4*)&Wp[(size_t)(jb2 * 64 + (idx >> 4)) * DD + db2 * 64 + ((idx & 15) << 2)];
        }
      }
      __syncthreads();
      float (*acc)[2] = (jb == 0) ? accA : accB;
#pragma unroll 4
      for (int d0 = 0; d0 < 64; d0 += 4) {
        float4 av[2], wv[4];
#pragma unroll
        for (int q = 0; q < 2; ++q) av[q] = *(const float4*)&sv[tl * 2 + q][db * 64 + d0];
#pragma unroll
        for (int j = 0; j < 4; ++j) wv[j] = *(const float4*)&sW[tc + 16 * j][d0];
#pragma unroll
        for (int j = 0; j < 4; ++j)
#pragma unroll
          for (int q = 0; q < 2; ++q)
            acc[j][q] += av[q].x * wv[j].x + av[q].y * wv[j].y + av[q].z * wv[j].z + av[q].w * wv[j].w;
      }
    }
  }
#pragma unroll
  for (int jb = 0; jb < 2; ++jb)
#pragma unroll
    for (int j = 0; j < 4; ++j)
#pragma unroll
      for (int q = 0; q < 2; ++q) {
        const int col = jb * 64 + tc + 16 * j;
        const float u = ((jb == 0) ? accA[j][q] : accB[j][q]) + sbias[col];
        dst[(size_t)(tl * 2 + q) * DD + col] = rv[jb * 8 + j * 2 + q] + gelu_(u);
      }
}

extern "C" void kernel_launch(void* const* d_in, const int* in_sizes, int n_in,
                              void* d_out, int out_size, void* d_ws, size_t ws_size,
                              hipStream_t stream) {
  (void)in_sizes; (void)n_in; (void)out_size; (void)ws_size;
  const float* sar    = (const float*)d_in[0];
  const float* opt    = (const float*)d_in[1];
  const float* in_w   = (const float*)d_in[2];
  const float* conv_w = (const float*)d_in[3];
  const float* conv_b = (const float*)d_in[4];
  const float* xproj_w= (const float*)d_in[5];
  const float* dt_w   = (const float*)d_in[6];
  const float* dt_b   = (const float*)d_in[7];
  const float* Alogs  = (const float*)d_in[8];
  const float* Ds     = (const float*)d_in[9];
  const float* ln_g   = (const float*)d_in[10];
  const float* ln_b   = (const float*)d_in[11];
  const float* out_w  = (const float*)d_in[12];
  const float* eg     = (const float*)d_in[13];
  const float* eb     = (const float*)d_in[14];
  const float* ew     = (const float*)d_in[15];
  const float* ebias  = (const float*)d_in[16];

  float* ws     = (float*)d_ws;
  float* xz     = ws;                  // 8,388,608
  float* xc     = xz + 8388608;        // 4,194,304
  float* xdbl   = xc + 4194304;        // 3,145,728
  float* y0b    = xdbl + 3145728;      // 4,194,304
  float* y1b    = y0b + 4194304;       // 4,194,304
  float* y2b    = y1b + 4194304;       // 4,194,304
  float* y3b    = y2b + 4194304;       // 4,194,304
  float* guided = y3b + 4194304;       // 4,194,304
  float* hend   = guided + 4194304;    // 32*128*1024 = 4,194,304
  float* Pseg   = hend + 4194304;      // 4,194,304
  float* hin    = Pseg + 4194304;      // 4,194,304
  float* outf   = (float*)d_out;

  k_inproj <<<dim3(64, 4, 8), 256, 0, stream>>>(sar, opt, in_w, xz);
  k_conv   <<<dim3(4, 16, 8), 256, 0, stream>>>(xz, conv_w, conv_b, xc);
  k_xproj  <<<dim3(64, 4, 8), 256, 0, stream>>>(xc, xproj_w, xdbl);
  k_scan1  <<<dim3(128, 2, 8), 128, 0, stream>>>(xc, xdbl, dt_w, dt_b, Alogs, hend, Pseg);
  k_scan2  <<<dim3(128), 256, 0, stream>>>(hend, Pseg, hin);
  k_scan3  <<<dim3(128, 2, 8), 128, 0, stream>>>(xc, xdbl, dt_w, dt_b, Alogs, Ds, hin,
                                                 y0b, y1b, y2b, y3b);
  k_outproj<<<dim3(128, 8), 256, 0, stream>>>(y0b, y1b, y2b, y3b, xz, ln_g, ln_b, out_w, guided);
  k_enhance<<<dim3(128, 8), 256, 0, stream>>>(guided, eg, eb, ew, ebias, sar, opt, outf);
}

// Round 11
// 265.368 us; speedup vs baseline: 5.4982x; 1.0002x over previous
//
#include <hip/hip_runtime.h>
#include <hip/hip_bf16.h>
#include <math.h>

#define DEV __device__ __forceinline__

static constexpr int LL = 4096;   // H*W
static constexpr int DD = 128;    // hidden
static constexpr int SEG = 128;   // segments per scan (32 positions each)
static constexpr float LOG2E = 1.4426950408889634f;
static constexpr float LN2 = 0.6931471805599453f;

DEV float silu_(float x) { return x / (1.f + __expf(-x)); }
// A&S 7.1.26 erf approximation, |err| <= 1.5e-7
DEV float erf_(float x) {
  const float ax = fabsf(x);
  const float t = 1.f / fmaf(0.3275911f, ax, 1.f);
  float p = fmaf(1.061405429f, t, -1.453152027f);
  p = fmaf(p, t, 1.421413741f);
  p = fmaf(p, t, -0.284496736f);
  p = fmaf(p, t, 0.254829592f);
  p = p * t;
  const float r = 1.f - p * __expf(-ax * ax);
  return x < 0.f ? -r : r;
}
DEV float gelu_(float x) { return 0.5f * x * (1.f + erf_(x * 0.7071067811865475f)); }
DEV float sp_(float x) {
  const float t = __builtin_amdgcn_exp2f(-fabsf(x) * LOG2E);
  return fmaxf(x, 0.f) + LN2 * __builtin_amdgcn_logf(1.f + t);
}

template <int CTRL>
DEV float dpp_add_(float x) {
  int y = __builtin_amdgcn_update_dpp(0, __float_as_int(x), CTRL, 0xF, 0xF, true);
  return x + __int_as_float(y);
}

// 64-position tiles (used by x_proj): tile s of direction k
DEV void seg_base_step(int k, int s, int& base, int& step) {
  if (k == 0)      { base = s * 64;        step = 1;   }
  else if (k == 1) { base = s;             step = 64;  }
  else if (k == 2) { base = 4095 - s * 64; step = -1;  }
  else             { base = 4095 - s;      step = -64; }
}

// ---------------- K1: in_proj: xz[m][b][c][l] = x @ in_w^T (c-major out) ----
__global__ __launch_bounds__(256) void k_inproj(
    const float* __restrict__ sar, const float* __restrict__ opt,
    const float* __restrict__ in_w, float* __restrict__ xz) {
  const int lt = blockIdx.x, ct = blockIdx.y, mb = blockIdx.z;
  const int m = mb >> 2;
  const float* __restrict__ x = (m == 0 ? opt : sar) + (size_t)(mb & 3) * (LL * DD);
  const float* __restrict__ W = in_w + (size_t)m * 256 * DD;
  __shared__ float sA[64][68];
  __shared__ float sW[64][68];
  const int tid = threadIdx.x;
  const int tc = tid & 15, tl = tid >> 4;
  float acc[4][4] = {};
  for (int db = 0; db < 2; ++db) {
    __syncthreads();
    for (int idx = tid; idx < 64 * 16; idx += 256) {
      const int r = idx >> 4, d4 = (idx & 15) << 2;
      *(float4*)&sA[r][d4] = *(const float4*)&x[(size_t)(lt * 64 + r) * DD + db * 64 + d4];
      *(float4*)&sW[r][d4] = *(const float4*)&W[(size_t)(ct * 64 + r) * DD + db * 64 + d4];
    }
    __syncthreads();
#pragma unroll 4
    for (int d = 0; d < 64; d += 4) {
      float4 a[4], w[4];
#pragma unroll
      for (int q = 0; q < 4; ++q) a[q] = *(const float4*)&sA[tl * 4 + q][d];
#pragma unroll
      for (int j = 0; j < 4; ++j) w[j] = *(const float4*)&sW[tc + 16 * j][d];
#pragma unroll
      for (int j = 0; j < 4; ++j)
#pragma unroll
        for (int q = 0; q < 4; ++q)
          acc[j][q] += a[q].x * w[j].x + a[q].y * w[j].y + a[q].z * w[j].z + a[q].w * w[j].w;
    }
  }
  float* __restrict__ dst = xz + ((size_t)mb * 256 + ct * 64) * LL + lt * 64;
#pragma unroll
  for (int j = 0; j < 4; ++j) {
    float4 v = make_float4(acc[j][0], acc[j][1], acc[j][2], acc[j][3]);
    *(float4*)&dst[(size_t)(tc + 16 * j) * LL + tl * 4] = v;
  }
}

// ---------------- K2: depthwise 3x3 SAME conv + bias + SiLU ---------------
__global__ __launch_bounds__(256) void k_conv(
    const float* __restrict__ xz, const float* __restrict__ conv_w,
    const float* __restrict__ conv_b, float* __restrict__ xc) {
  const int ht = blockIdx.x, dg = blockIdx.y, mb = blockIdx.z;
  const int m = mb >> 2;
  __shared__ float sIn[8][18][66];
  __shared__ float sOut[1024][8];
  const float* __restrict__ src = xz + ((size_t)mb * 256 + dg * 8) * LL;
  const int tid = threadIdx.x;
  for (int idx = tid; idx < 8 * 18 * 66; idx += 256) {
    const int dd = idx / (18 * 66);
    const int rem = idx - dd * (18 * 66);
    const int hh = rem / 66, ww = rem - hh * 66;
    const int h = ht * 16 + hh - 1, w = ww - 1;
    float v = 0.f;
    if (h >= 0 && h < 64 && w >= 0 && w < 64) v = src[(size_t)dd * LL + h * 64 + w];
    sIn[dd][hh][ww] = v;
  }
  __syncthreads();
  const int dd = tid & 7, wv = tid >> 3;
  const int dch = dg * 8 + dd;
  float wk[9];
#pragma unroll
  for (int t = 0; t < 9; ++t) wk[t] = conv_w[((size_t)m * DD + dch) * 9 + t];
  const float bias = conv_b[m * DD + dch];
  for (int hh = 0; hh < 16; ++hh) {
#pragma unroll
    for (int wh = 0; wh < 2; ++wh) {
      const int w = wv + wh * 32;
      float s = bias;
#pragma unroll
      for (int kh = 0; kh < 3; ++kh)
#pragma unroll
        for (int kw = 0; kw < 3; ++kw)
          s = fmaf(sIn[dd][hh + kh][w + kw], wk[kh * 3 + kw], s);
      sOut[hh * 64 + w][dd] = silu_(s);
    }
  }
  __syncthreads();
  float* __restrict__ dst = xc + (size_t)mb * LL * DD + dg * 8;
#pragma unroll
  for (int r = 0; r < 4; ++r) {
    const int pos = tid + r * 256;
    const int l = ht * 1024 + pos;
    *(float4*)&dst[(size_t)l * DD + 0] = *(const float4*)&sOut[pos][0];
    *(float4*)&dst[(size_t)l * DD + 4] = *(const float4*)&sOut[pos][4];
  }
}

// ---------------- K3: x_proj -> xdbl[mbk][l][24]  (l-major, contiguous) ---
__global__ __launch_bounds__(256) void k_xproj(
    const float* __restrict__ xc, const float* __restrict__ xproj_w,
    float* __restrict__ xdbl) {
  const int lt = blockIdx.x, k = blockIdx.y, mb = blockIdx.z;
  const int m = mb >> 2, mbk = mb * 4 + k;
  __shared__ float sX[64][132];
  __shared__ float sW[24][132];
  const int tid = threadIdx.x;
  const float* __restrict__ src = xc + (size_t)mb * LL * DD;
  int base, step;
  seg_base_step(k, lt, base, step);
  for (int idx = tid; idx < 64 * 32; idx += 256) {
    const int l = idx >> 5, d4 = (idx & 31) << 2;
    *(float4*)&sX[l][d4] = *(const float4*)&src[(size_t)(base + l * step) * DD + d4];
  }
  const float* __restrict__ Wsrc = xproj_w + ((size_t)m * 4 + k) * 24 * DD;
  for (int idx = tid; idx < 24 * 32; idx += 256) {
    const int r = idx >> 5, d4 = (idx & 31) << 2;
    *(float4*)&sW[r][d4] = *(const float4*)&Wsrc[(size_t)r * DD + d4];
  }
  __syncthreads();
  const int l = tid >> 2, cg = tid & 3;
  float acc[6] = {};
#pragma unroll 8
  for (int d = 0; d < 128; d += 4) {
    const float4 xv = *(const float4*)&sX[l][d];
#pragma unroll
    for (int j = 0; j < 6; ++j) {
      const float4 wv = *(const float4*)&sW[cg * 6 + j][d];
      acc[j] += xv.x * wv.x + xv.y * wv.y + xv.z * wv.z + xv.w * wv.w;
    }
  }
  float* __restrict__ dst = xdbl + ((size_t)mbk * LL + lt * 64 + l) * 24 + cg * 6;
#pragma unroll
  for (int j = 0; j < 6; ++j) dst[j] = acc[j];
}

// ============== dual-chain segmented selective scan (SEGL=32) =============
// Block (s, p, mb): one 32-position physical strip (row for p=0, col for
// p=1). Chain A = direction p, segment s (walks strip forward); chain B =
// direction p+2, segment 127-s (walks strip backward). Per-step 24-float
// dts/B/C rows are read directly from GLOBAL at wave-uniform addresses
// (scalar/broadcast path; L1-resident) - no LDS staging. In pass 3, chain
// A's 32 y values stay in VGPRs and chain B adds them at store time, so
// each strip writes ONE combined buffer (yrow for p=0, ycol for p=1).

DEV void load_aln2(const float* __restrict__ Alogs, int m, int k, int d,
                   float* __restrict__ aln2, bool& fastp) {
  const float4 a0 = *(const float4*)&Alogs[((size_t)m * 512 + k * DD + d) * 8];
  const float4 a1 = *(const float4*)&Alogs[((size_t)m * 512 + k * DD + d) * 8 + 4];
  aln2[0] = -__expf(a0.x) * LOG2E; aln2[1] = -__expf(a0.y) * LOG2E;
  aln2[2] = -__expf(a0.z) * LOG2E; aln2[3] = -__expf(a0.w) * LOG2E;
  aln2[4] = -__expf(a1.x) * LOG2E; aln2[5] = -__expf(a1.y) * LOG2E;
  aln2[6] = -__expf(a1.z) * LOG2E; aln2[7] = -__expf(a1.w) * LOG2E;
  fastp = true;
#pragma unroll
  for (int n = 1; n < 8; ++n)
    fastp = fastp && (fabsf(aln2[n] - (float)(n + 1) * aln2[0]) <=
                      1e-4f * fabsf(aln2[n]) + 1e-12f);
}

DEV void load_w8(const float* __restrict__ dt_w, int mbk, int d,
                 float* __restrict__ wreg) {
  const float4 w0 = *(const float4*)&dt_w[((size_t)mbk * DD + d) * 8];
  const float4 w1 = *(const float4*)&dt_w[((size_t)mbk * DD + d) * 8 + 4];
  wreg[0] = w0.x; wreg[1] = w0.y; wreg[2] = w0.z; wreg[3] = w0.w;
  wreg[4] = w1.x; wreg[5] = w1.y; wreg[6] = w1.z; wreg[7] = w1.w;
}

template <bool FAST>
DEV void qpow_(float dt, const float* __restrict__ aln2, float* __restrict__ q) {
  if constexpr (FAST) {
    q[0] = __builtin_amdgcn_exp2f(dt * aln2[0]);
    q[1] = q[0] * q[0]; q[2] = q[1] * q[0]; q[3] = q[1] * q[1];
    q[4] = q[3] * q[0]; q[5] = q[3] * q[1]; q[6] = q[3] * q[2]; q[7] = q[3] * q[3];
  } else {
#pragma unroll
    for (int n = 0; n < 8; ++n) q[n] = __builtin_amdgcn_exp2f(dt * aln2[n]);
  }
}

// t24 = uniform pointer to this step's 24-float row {dts[8], B[8], C[8]}
DEV float dt_of_(const float* __restrict__ t24,
                 const float* __restrict__ w, float bw) {
  const float4 t0 = *(const float4*)&t24[0];
  const float4 t1 = *(const float4*)&t24[4];
  float s = bw;
  s = fmaf(t0.x, w[0], s); s = fmaf(t0.y, w[1], s);
  s = fmaf(t0.z, w[2], s); s = fmaf(t0.w, w[3], s);
  s = fmaf(t1.x, w[4], s); s = fmaf(t1.y, w[5], s);
  s = fmaf(t1.z, w[6], s); s = fmaf(t1.w, w[7], s);
  return sp_(s);
}

template <bool FAST>
DEV void hstep_(const float* __restrict__ t24, float dt, float x,
                const float* __restrict__ aln2, float* __restrict__ h) {
  const float u = dt * x;
  float q[8];
  qpow_<FAST>(dt, aln2, q);
  const float4 b0 = *(const float4*)&t24[8];
  const float4 b1 = *(const float4*)&t24[12];
  h[0] = fmaf(h[0], q[0], u * b0.x);
  h[1] = fmaf(h[1], q[1], u * b0.y);
  h[2] = fmaf(h[2], q[2], u * b0.z);
  h[3] = fmaf(h[3], q[3], u * b0.w);
  h[4] = fmaf(h[4], q[4], u * b1.x);
  h[5] = fmaf(h[5], q[5], u * b1.y);
  h[6] = fmaf(h[6], q[6], u * b1.z);
  h[7] = fmaf(h[7], q[7], u * b1.w);
}

template <bool FAST>
DEV float ystep_(const float* __restrict__ t24, float dt, float x,
                 const float* __restrict__ aln2, float dsv,
                 float* __restrict__ h) {
  const float u = dt * x;
  float q[8];
  qpow_<FAST>(dt, aln2, q);
  const float4 b0 = *(const float4*)&t24[8];
  const float4 b1 = *(const float4*)&t24[12];
  const float4 c0 = *(const float4*)&t24[16];
  const float4 c1 = *(const float4*)&t24[20];
  float y = dsv * x;
  h[0] = fmaf(h[0], q[0], u * b0.x); y = fmaf(h[0], c0.x, y);
  h[1] = fmaf(h[1], q[1], u * b0.y); y = fmaf(h[1], c0.y, y);
  h[2] = fmaf(h[2], q[2], u * b0.z); y = fmaf(h[2], c0.z, y);
  h[3] = fmaf(h[3], q[3], u * b0.w); y = fmaf(h[3], c0.w, y);
  h[4] = fmaf(h[4], q[4], u * b1.x); y = fmaf(h[4], c1.x, y);
  h[5] = fmaf(h[5], q[5], u * b1.y); y = fmaf(h[5], c1.y, y);
  h[6] = fmaf(h[6], q[6], u * b1.z); y = fmaf(h[6], c1.z, y);
  h[7] = fmaf(h[7], q[7], u * b1.w); y = fmaf(h[7], c1.w, y);
  return y;
}

// ---- pass 1: dual-chain local scan (h0=0) -> h_end, P --------------------
template <bool FAST>
DEV void loop1d_(const float* __restrict__ tA, const float* __restrict__ tB,
                 const float* __restrict__ sx, int d,
                 const float* __restrict__ aln2A, const float* __restrict__ aln2B,
                 const float* __restrict__ wA, const float* __restrict__ wB,
                 float bwA, float bwB, float* __restrict__ hA,
                 float* __restrict__ hB, float& dtsA, float& dtsB) {
#pragma unroll 8
  for (int j = 0; j < 32; ++j) {
    const float xA = sx[j * 128 + d];
    const float xB = sx[(31 - j) * 128 + d];
    const float dtA = dt_of_(tA + j * 24, wA, bwA);
    const float dtB = dt_of_(tB + j * 24, wB, bwB);
    dtsA += dtA; dtsB += dtB;
    hstep_<FAST>(tA + j * 24, dtA, xA, aln2A, hA);
    hstep_<FAST>(tB + j * 24, dtB, xB, aln2B, hB);
  }
}

__global__ __launch_bounds__(128) void k_scan1(
    const float* __restrict__ xc, const float* __restrict__ xdbl,
    const float* __restrict__ dt_w, const float* __restrict__ dt_b,
    const float* __restrict__ Alogs, float* __restrict__ hend,
    float* __restrict__ Pseg) {
  const int s = blockIdx.x, p = blockIdx.y, mb = blockIdx.z;
  const int m = mb >> 2;
  const int kA = p, kB = p + 2;
  const int sA = s, sB = 127 - s;
  const int mbkA = mb * 4 + kA, mbkB = mb * 4 + kB;
  const int d = threadIdx.x;
  __shared__ float sx[32 * 128];   // 16 KB

  const float* __restrict__ tA = xdbl + ((size_t)mbkA * LL + sA * 32) * 24;
  const float* __restrict__ tB = xdbl + ((size_t)mbkB * LL + sB * 32) * 24;

  const int base0 = (p == 0) ? s * 32 : ((s & 1) * 32) * 64 + (s >> 1);
  const int stepPos = (p == 0) ? 1 : 64;
  const float* __restrict__ xsrc = xc + (size_t)mb * LL * DD;
#pragma unroll
  for (int t = 0; t < 8; ++t) {
    const int idx = d + t * 128;
    const int r = idx >> 5, c4 = (idx & 31) << 2;
    ((float4*)sx)[idx] = *(const float4*)&xsrc[(size_t)(base0 + r * stepPos) * DD + c4];
  }

  float aln2A[8], aln2B[8]; bool fA, fB;
  load_aln2(Alogs, m, kA, d, aln2A, fA);
  load_aln2(Alogs, m, kB, d, aln2B, fB);
  float wA[8], wB[8];
  load_w8(dt_w, mbkA, d, wA);
  load_w8(dt_w, mbkB, d, wB);
  const float bwA = dt_b[(size_t)mbkA * DD + d];
  const float bwB = dt_b[(size_t)mbkB * DD + d];
  __syncthreads();

  float hA[8] = {0, 0, 0, 0, 0, 0, 0, 0};
  float hB[8] = {0, 0, 0, 0, 0, 0, 0, 0};
  float dtsA = 0.f, dtsB = 0.f;
  if (fA && fB)
    loop1d_<true>(tA, tB, sx, d, aln2A, aln2B, wA, wB, bwA, bwB, hA, hB, dtsA, dtsB);
  else
    loop1d_<false>(tA, tB, sx, d, aln2A, aln2B, wA, wB, bwA, bwB, hA, hB, dtsA, dtsB);

  {
    float* __restrict__ he = hend + (((size_t)mbkA * SEG + sA) << 10) + d * 8;
    float* __restrict__ pe = Pseg + (((size_t)mbkA * SEG + sA) << 10) + d * 8;
    *(float4*)&he[0] = make_float4(hA[0], hA[1], hA[2], hA[3]);
    *(float4*)&he[4] = make_float4(hA[4], hA[5], hA[6], hA[7]);
    *(float4*)&pe[0] = make_float4(
        __builtin_amdgcn_exp2f(aln2A[0] * dtsA), __builtin_amdgcn_exp2f(aln2A[1] * dtsA),
        __builtin_amdgcn_exp2f(aln2A[2] * dtsA), __builtin_amdgcn_exp2f(aln2A[3] * dtsA));
    *(float4*)&pe[4] = make_float4(
        __builtin_amdgcn_exp2f(aln2A[4] * dtsA), __builtin_amdgcn_exp2f(aln2A[5] * dtsA),
        __builtin_amdgcn_exp2f(aln2A[6] * dtsA), __builtin_amdgcn_exp2f(aln2A[7] * dtsA));
  }
  {
    float* __restrict__ he = hend + (((size_t)mbkB * SEG + sB) << 10) + d * 8;
    float* __restrict__ pe = Pseg + (((size_t)mbkB * SEG + sB) << 10) + d * 8;
    *(float4*)&he[0] = make_float4(hB[0], hB[1], hB[2], hB[3]);
    *(float4*)&he[4] = make_float4(hB[4], hB[5], hB[6], hB[7]);
    *(float4*)&pe[0] = make_float4(
        __builtin_amdgcn_exp2f(aln2B[0] * dtsB), __builtin_amdgcn_exp2f(aln2B[1] * dtsB),
        __builtin_amdgcn_exp2f(aln2B[2] * dtsB), __builtin_amdgcn_exp2f(aln2B[3] * dtsB));
    *(float4*)&pe[4] = make_float4(
        __builtin_amdgcn_exp2f(aln2B[4] * dtsB), __builtin_amdgcn_exp2f(aln2B[5] * dtsB),
        __builtin_amdgcn_exp2f(aln2B[6] * dtsB), __builtin_amdgcn_exp2f(aln2B[7] * dtsB));
  }
}

// ---- pass 2: sequential combine across 128 segments -> h_in --------------
// Loads batched 16-deep to hide latency of the strided dependent walk.
__global__ __launch_bounds__(256) void k_scan2(
    const float* __restrict__ hend, const float* __restrict__ Pseg,
    float* __restrict__ hin) {
  const int gid = blockIdx.x * 256 + threadIdx.x;   // 32768
  const int mbk = gid >> 10, dn = gid & 1023;
  const float* __restrict__ P = Pseg + ((size_t)mbk * SEG << 10) + dn;
  const float* __restrict__ E = hend + ((size_t)mbk * SEG << 10) + dn;
  float* __restrict__ O = hin + ((size_t)mbk * SEG << 10) + dn;
  float h = 0.f;
  for (int c0 = 0; c0 < SEG; c0 += 16) {
    float pv[16], ev[16];
#pragma unroll
    for (int t = 0; t < 16; ++t) {
      pv[t] = P[(size_t)(c0 + t) << 10];
      ev[t] = E[(size_t)(c0 + t) << 10];
    }
#pragma unroll
    for (int t = 0; t < 16; ++t) {
      O[(size_t)(c0 + t) << 10] = h;
      h = fmaf(pv[t], h, ev[t]);
    }
  }
}

// ---- pass 3: dual-chain seeded scan; chains combined in registers --------
template <bool FAST>
DEV void chainA_(const float* __restrict__ t24, const float* __restrict__ sx, int d,
                 const float* __restrict__ aln2, const float* __restrict__ w,
                 float bw, float dsv, float* __restrict__ h,
                 float* __restrict__ va) {
#pragma unroll
  for (int j = 0; j < 32; ++j) {
    const float x = sx[j * 128 + d];
    const float dt = dt_of_(t24 + j * 24, w, bw);
    va[j] = ystep_<FAST>(t24 + j * 24, dt, x, aln2, dsv, h);
  }
}

template <bool FAST>
DEV void chainB_(const float* __restrict__ t24, const float* __restrict__ sx, int d,
                 const float* __restrict__ aln2, const float* __restrict__ w,
                 float bw, float dsv, float* __restrict__ h,
                 const float* __restrict__ va, float* __restrict__ yd,
                 ptrdiff_t sstep) {
#pragma unroll
  for (int j = 0; j < 32; ++j) {
    const int phys = 31 - j;
    const float x = sx[phys * 128 + d];
    const float dt = dt_of_(t24 + j * 24, w, bw);
    const float v = ystep_<FAST>(t24 + j * 24, dt, x, aln2, dsv, h);
    yd[(ptrdiff_t)phys * sstep] = v + va[phys];
  }
}

__global__ __launch_bounds__(128) void k_scan3(
    const float* __restrict__ xc, const float* __restrict__ xdbl,
    const float* __restrict__ dt_w, const float* __restrict__ dt_b,
    const float* __restrict__ Alogs, const float* __restrict__ Ds,
    const float* __restrict__ hin, float* __restrict__ yrow,
    float* __restrict__ ycol) {
  const int s = blockIdx.x, p = blockIdx.y, mb = blockIdx.z;
  const int m = mb >> 2;
  const int kA = p, kB = p + 2;
  const int sA = s, sB = 127 - s;
  const int mbkA = mb * 4 + kA, mbkB = mb * 4 + kB;
  const int d = threadIdx.x;
  __shared__ float sx[32 * 128];   // 16 KB

  const float* __restrict__ tA = xdbl + ((size_t)mbkA * LL + sA * 32) * 24;
  const float* __restrict__ tB = xdbl + ((size_t)mbkB * LL + sB * 32) * 24;

  const int base0 = (p == 0) ? s * 32 : ((s & 1) * 32) * 64 + (s >> 1);
  const int stepPos = (p == 0) ? 1 : 64;
  const float* __restrict__ xsrc = xc + (size_t)mb * LL * DD;
#pragma unroll
  for (int t = 0; t < 8; ++t) {
    const int idx = d + t * 128;
    const int r = idx >> 5, c4 = (idx & 31) << 2;
    ((float4*)sx)[idx] = *(const float4*)&xsrc[(size_t)(base0 + r * stepPos) * DD + c4];
  }

  float aln2A[8], aln2B[8]; bool fA, fB;
  load_aln2(Alogs, m, kA, d, aln2A, fA);
  load_aln2(Alogs, m, kB, d, aln2B, fB);
  float wA[8], wB[8];
  load_w8(dt_w, mbkA, d, wA);
  load_w8(dt_w, mbkB, d, wB);
  const float bwA = dt_b[(size_t)mbkA * DD + d];
  const float bwB = dt_b[(size_t)mbkB * DD + d];
  const float dsvA = Ds[(size_t)m * 512 + kA * DD + d];
  const float dsvB = Ds[(size_t)m * 512 + kB * DD + d];

  float hA[8], hB[8];
  {
    const float* hp = hin + (((size_t)mbkA * SEG + sA) << 10) + d * 8;
    const float4 h0 = *(const float4*)&hp[0];
    const float4 h1 = *(const float4*)&hp[4];
    hA[0] = h0.x; hA[1] = h0.y; hA[2] = h0.z; hA[3] = h0.w;
    hA[4] = h1.x; hA[5] = h1.y; hA[6] = h1.z; hA[7] = h1.w;
  }
  {
    const float* hp = hin + (((size_t)mbkB * SEG + sB) << 10) + d * 8;
    const float4 h0 = *(const float4*)&hp[0];
    const float4 h1 = *(const float4*)&hp[4];
    hB[0] = h0.x; hB[1] = h0.y; hB[2] = h0.z; hB[3] = h0.w;
    hB[4] = h1.x; hB[5] = h1.y; hB[6] = h1.z; hB[7] = h1.w;
  }

  const size_t off0 = (size_t)mb * LL * DD + (size_t)base0 * DD + d;
  float* __restrict__ yd = (p == 0 ? yrow : ycol) + off0;
  const ptrdiff_t sstep = (ptrdiff_t)stepPos * DD;
  __syncthreads();

  float va[32];
  if (fA) chainA_<true>(tA, sx, d, aln2A, wA, bwA, dsvA, hA, va);
  else    chainA_<false>(tA, sx, d, aln2A, wA, bwA, dsvA, hA, va);
  if (fB) chainB_<true>(tB, sx, d, aln2B, wB, bwB, dsvB, hB, va, yd, sstep);
  else    chainB_<false>(tB, sx, d, aln2B, wB, bwB, dsvB, hB, va, yd, sstep);
}

// ---------------- K6: LN(yrow+ycol) * silu(z) @ out_w^T -> guided ---------
__global__ __launch_bounds__(256) void k_outproj(
    const float* __restrict__ yrow, const float* __restrict__ ycol,
    const float* __restrict__ xz, const float* __restrict__ ln_g,
    const float* __restrict__ ln_b, const float* __restrict__ out_w,
    float* __restrict__ guided) {
  const int lt = blockIdx.x, mb = blockIdx.y;
  const int m = mb >> 2;
  __shared__ float sv[32][132];
  __shared__ float sW[64][68];
  __shared__ float smr[32][2];
  __shared__ float sg[128], sb[128];
  const int tid = threadIdx.x;
  const size_t yoff = ((size_t)mb * LL + lt * 32) * DD;
  const float4* p0 = (const float4*)(yrow + yoff);
  const float4* p1 = (const float4*)(ycol + yoff);
  float4 ya[4], yb[4];
#pragma unroll
  for (int t = 0; t < 4; ++t) { ya[t] = p0[tid + t * 256]; yb[t] = p1[tid + t * 256]; }
  const int zc = tid >> 1, zh = tid & 1;
  const float4* zsrc = (const float4*)(xz + ((size_t)mb * 256 + 128 + zc) * LL + lt * 32 + zh * 16);
  float4 zv[4];
#pragma unroll
  for (int t = 0; t < 4; ++t) zv[t] = zsrc[t];
  const float* __restrict__ Wp = out_w + (size_t)m * DD * DD;
  float4 wpre[4];
#pragma unroll
  for (int t = 0; t < 4; ++t) {
    const int idx = tid + t * 256;
    wpre[t] = *(const float4*)&Wp[(size_t)(idx >> 4) * DD + ((idx & 15) << 2)];
  }
  if (tid < 128) { sg[tid] = ln_g[m * DD + tid]; sb[tid] = ln_b[m * DD + tid]; }
#pragma unroll
  for (int t = 0; t < 4; ++t) {
    const int idx = tid + t * 256;
    float4 v;
    v.x = ya[t].x + yb[t].x; v.y = ya[t].y + yb[t].y;
    v.z = ya[t].z + yb[t].z; v.w = ya[t].w + yb[t].w;
    *(float4*)&sv[idx >> 5][(idx & 31) << 2] = v;
  }
  __syncthreads();
  {
    const int l = tid >> 3, q = tid & 7;
    float s = 0.f, s2 = 0.f;
#pragma unroll
    for (int d0 = 0; d0 < 16; d0 += 4) {
      const float4 v = *(const float4*)&sv[l][q * 16 + d0];
      s += v.x + v.y + v.z + v.w;
      s2 += v.x * v.x + v.y * v.y + v.z * v.z + v.w * v.w;
    }
    s = dpp_add_<0xB1>(s); s = dpp_add_<0x4E>(s); s = dpp_add_<0x141>(s);
    s2 = dpp_add_<0xB1>(s2); s2 = dpp_add_<0x4E>(s2); s2 = dpp_add_<0x141>(s2);
    if (q == 0) {
      const float mean = s * (1.f / 128.f);
      smr[l][0] = mean;
      smr[l][1] = rsqrtf(fmaf(s2, 1.f / 128.f, -mean * mean) + 1e-5f);
    }
  }
  __syncthreads();
  {
    const float g = sg[zc], bb = sb[zc];
    const float* zf = (const float*)zv;
#pragma unroll
    for (int i2 = 0; i2 < 16; ++i2) {
      const int l = zh * 16 + i2;
      const float v = fmaf((sv[l][zc] - smr[l][0]) * smr[l][1], g, bb);
      sv[l][zc] = v * silu_(zf[i2]);
    }
  }
  const int tc = tid & 15, tl = tid >> 4;
  float* __restrict__ dst = guided + ((size_t)mb * LL + lt * 32) * DD;
#pragma unroll
  for (int jb = 0; jb < 2; ++jb) {
    float acc[4][2] = {};
#pragma unroll
    for (int db = 0; db < 2; ++db) {
      __syncthreads();
#pragma unroll
      for (int t = 0; t < 4; ++t) {
        const int idx = tid + t * 256;
        *(float4*)&sW[idx >> 4][(idx & 15) << 2] = wpre[t];
      }
      const int ph = jb * 2 + db + 1;
      if (ph < 4) {
        const int jb2 = ph >> 1, db2 = ph & 1;
#pragma unroll
        for (int t = 0; t < 4; ++t) {
          const int idx = tid + t * 256;
          wpre[t] = *(const float4*)&Wp[(size_t)(jb2 * 64 + (idx >> 4)) * DD + db2 * 64 + ((idx & 15) << 2)];
        }
      }
      __syncthreads();
#pragma unroll 4
      for (int d0 = 0; d0 < 64; d0 += 4) {
        float4 av[2], wv[4];
#pragma unroll
        for (int q = 0; q < 2; ++q) av[q] = *(const float4*)&sv[tl * 2 + q][db * 64 + d0];
#pragma unroll
        for (int j = 0; j < 4; ++j) wv[j] = *(const float4*)&sW[tc + 16 * j][d0];
#pragma unroll
        for (int j = 0; j < 4; ++j)
#pragma unroll
          for (int q = 0; q < 2; ++q)
            acc[j][q] += av[q].x * wv[j].x + av[q].y * wv[j].y + av[q].z * wv[j].z + av[q].w * wv[j].w;
      }
    }
#pragma unroll
    for (int j = 0; j < 4; ++j)
#pragma unroll
      for (int q = 0; q < 2; ++q)
        dst[(size_t)(tl * 2 + q) * DD + jb * 64 + tc + 16 * j] = acc[j][q];
  }
}

// ---------------- K7: enhance (LN -> GEMM -> +bias -> GELU -> +residual) --
__global__ __launch_bounds__(256) void k_enhance(
    const float* __restrict__ guided, const float* __restrict__ eg,
    const float* __restrict__ ebv, const float* __restrict__ ew,
    const float* __restrict__ ebias, const float* __restrict__ sar,
    const float* __restrict__ opt, float* __restrict__ outp) {
  const int lt = blockIdx.x, ib = blockIdx.y;
  const int i = ib >> 2, b = ib & 3;
  __shared__ float sv[32][132];
  __shared__ float sW[64][68];
  __shared__ float smr[32][2];
  __shared__ float sg[128], sb2[128], sbias[128];
  const int tid = threadIdx.x;
  const float4* gsrc =
      (const float4*)(guided + (((size_t)(1 - i) * 4 + b) * LL + lt * 32) * DD);
  float4 gv[4];
#pragma unroll
  for (int t = 0; t < 4; ++t) gv[t] = gsrc[tid + t * 256];
  const float* __restrict__ Wp = ew + (size_t)i * DD * DD;
  float4 wpre[4];
#pragma unroll
  for (int t = 0; t < 4; ++t) {
    const int idx = tid + t * 256;
    wpre[t] = *(const float4*)&Wp[(size_t)(idx >> 4) * DD + ((idx & 15) << 2)];
  }
  if (tid < 128) {
    sg[tid] = eg[i * DD + tid];
    sb2[tid] = ebv[i * DD + tid];
    sbias[tid] = ebias[i * DD + tid];
  }
#pragma unroll
  for (int t = 0; t < 4; ++t) {
    const int idx = tid + t * 256;
    *(float4*)&sv[idx >> 5][(idx & 31) << 2] = gv[t];
  }
  __syncthreads();
  {
    const int l = tid >> 3, q = tid & 7;
    float s = 0.f, s2 = 0.f;
#pragma unroll
    for (int d0 = 0; d0 < 16; d0 += 4) {
      const float4 v = *(const float4*)&sv[l][q * 16 + d0];
      s += v.x + v.y + v.z + v.w;
      s2 += v.x * v.x + v.y * v.y + v.z * v.z + v.w * v.w;
    }
    s = dpp_add_<0xB1>(s); s = dpp_add_<0x4E>(s); s = dpp_add_<0x141>(s);
    s2 = dpp_add_<0xB1>(s2); s2 = dpp_add_<0x4E>(s2); s2 = dpp_add_<0x141>(s2);
    if (q == 0) {
      const float mean = s * (1.f / 128.f);
      smr[l][0] = mean;
      smr[l][1] = rsqrtf(fmaf(s2, 1.f / 128.f, -mean * mean) + 1e-5f);
    }
  }
  __syncthreads();
  {
    const int c = tid >> 1, half = tid & 1;
    const float g = sg[c], bb = sb2[c];
#pragma unroll
    for (int i2 = 0; i2 < 16; ++i2) {
      const int l = half * 16 + i2;
      sv[l][c] = fmaf((sv[l][c] - smr[l][0]) * smr[l][1], g, bb);
    }
  }
  const int tc = tid & 15, tl = tid >> 4;
  const float* __restrict__ resid = (i == 0 ? sar : opt) + ((size_t)b * LL + lt * 32) * DD;
  float* __restrict__ dst = outp + (size_t)i * (4 * LL * DD) + ((size_t)b * LL + lt * 32) * DD;
  float rv[16];
#pragma unroll
  for (int jb = 0; jb < 2; ++jb)
#pragma unroll
    for (int j = 0; j < 4; ++j)
#pragma unroll
      for (int q = 0; q < 2; ++q)
        rv[jb * 8 + j * 2 + q] = resid[(size_t)(tl * 2 + q) * DD + jb * 64 + tc + 16 * j];
  float accA[4][2] = {}, accB[4][2] = {};
#pragma unroll
  for (int jb = 0; jb < 2; ++jb) {
#pragma unroll
    for (int db = 0; db < 2; ++db) {
      __syncthreads();
#pragma unroll
      for (int t = 0; t < 4; ++t) {
        const int idx = tid + t * 256;
        *(float4*)&sW[idx >> 4][(idx & 15) << 2] = wpre[t];
      }
      const int ph = jb * 2 + db + 1;
      if (ph < 4) {
        const int jb2 = ph >> 1, db2 = ph & 1;
#pragma unroll
        for (int t = 0; t < 4; ++t) {
          const int idx = tid + t * 256;
          wpre[t] = *(const float4*)&Wp[(size_t)(jb2 * 64 + (idx >> 4)) * DD + db2 * 64 + ((idx & 15) << 2)];
        }
      }
      __syncthreads();
      float (*acc)[2] = (jb == 0) ? accA : accB;
#pragma unroll 4
      for (int d0 = 0; d0 < 64; d0 += 4) {
        float4 av[2], wv[4];
#pragma unroll
        for (int q = 0; q < 2; ++q) av[q] = *(const float4*)&sv[tl * 2 + q][db * 64 + d0];
#pragma unroll
        for (int j = 0; j < 4; ++j) wv[j] = *(const float4*)&sW[tc + 16 * j][d0];
#pragma unroll
        for (int j = 0; j < 4; ++j)
#pragma unroll
          for (int q = 0; q < 2; ++q)
            acc[j][q] += av[q].x * wv[j].x + av[q].y * wv[j].y + av[q].z * wv[j].z + av[q].w * wv[j].w;
      }
    }
  }
#pragma unroll
  for (int jb = 0; jb < 2; ++jb)
#pragma unroll
    for (int j = 0; j < 4; ++j)
#pragma unroll
      for (int q = 0; q < 2; ++q) {
        const int col = jb * 64 + tc + 16 * j;
        const float u = ((jb == 0) ? accA[j][q] : accB[j][q]) + sbias[col];
        dst[(size_t)(tl * 2 + q) * DD + col] = rv[jb * 8 + j * 2 + q] + gelu_(u);
      }
}

extern "C" void kernel_launch(void* const* d_in, const int* in_sizes, int n_in,
                              void* d_out, int out_size, void* d_ws, size_t ws_size,
                              hipStream_t stream) {
  (void)in_sizes; (void)n_in; (void)out_size; (void)ws_size;
  const float* sar    = (const float*)d_in[0];
  const float* opt    = (const float*)d_in[1];
  const float* in_w   = (const float*)d_in[2];
  const float* conv_w = (const float*)d_in[3];
  const float* conv_b = (const float*)d_in[4];
  const float* xproj_w= (const float*)d_in[5];
  const float* dt_w   = (const float*)d_in[6];
  const float* dt_b   = (const float*)d_in[7];
  const float* Alogs  = (const float*)d_in[8];
  const float* Ds     = (const float*)d_in[9];
  const float* ln_g   = (const float*)d_in[10];
  const float* ln_b   = (const float*)d_in[11];
  const float* out_w  = (const float*)d_in[12];
  const float* eg     = (const float*)d_in[13];
  const float* eb     = (const float*)d_in[14];
  const float* ew     = (const float*)d_in[15];
  const float* ebias  = (const float*)d_in[16];

  float* ws     = (float*)d_ws;
  float* xz     = ws;                  // 8,388,608
  float* xc     = xz + 8388608;        // 4,194,304
  float* xdbl   = xc + 4194304;        // 3,145,728
  float* yrowb  = xdbl + 3145728;      // 4,194,304
  float* ycolb  = yrowb + 4194304;     // 4,194,304
  float* guided = ycolb + 4194304;     // 4,194,304
  float* hend   = guided + 4194304;    // 32*128*1024 = 4,194,304
  float* Pseg   = hend + 4194304;      // 4,194,304
  float* hin    = Pseg + 4194304;      // 4,194,304
  float* outf   = (float*)d_out;

  k_inproj <<<dim3(64, 4, 8), 256, 0, stream>>>(sar, opt, in_w, xz);
  k_conv   <<<dim3(4, 16, 8), 256, 0, stream>>>(xz, conv_w, conv_b, xc);
  k_xproj  <<<dim3(64, 4, 8), 256, 0, stream>>>(xc, xproj_w, xdbl);
  k_scan1  <<<dim3(128, 2, 8), 128, 0, stream>>>(xc, xdbl, dt_w, dt_b, Alogs, hend, Pseg);
  k_scan2  <<<dim3(128), 256, 0, stream>>>(hend, Pseg, hin);
  k_scan3  <<<dim3(128, 2, 8), 128, 0, stream>>>(xc, xdbl, dt_w, dt_b, Alogs, Ds, hin,
                                                 yrowb, ycolb);
  k_outproj<<<dim3(128, 8), 256, 0, stream>>>(yrowb, ycolb, xz, ln_g, ln_b, out_w, guided);
  k_enhance<<<dim3(128, 8), 256, 0, stream>>>(guided, eg, eb, ew, ebias, sar, opt, outf);
}